// Round 9
// baseline (114.347 us; speedup 1.0000x reference)
//
#include <hip/hip_runtime.h>
#include <math.h>

typedef unsigned short u16;
typedef unsigned long long u64;
typedef float    f32x4  __attribute__((ext_vector_type(4)));
typedef __bf16   bf16x8 __attribute__((ext_vector_type(8)));

#define NS    32768
#define KC    1024
#define INV_T 100.0f
#define TAU   2.0f

// ws layout (float offsets)
#define C2_OFF   0
#define SUMM_OFF 1024                      // [n][16 halfblocks] float4
#define SUMM_SZ  (NS * 16 * 4)
#define HIST_OFF (SUMM_OFF + SUMM_SZ)
#define PD_OFF   (HIST_OFF + KC)
#define PS_OFF   (PD_OFF + 8192)

// ct: tiled bf16 codebook, 16 tiles (64 codes) x 2048 chunks x 16B = 512 KB
// (lives in d_out, overwritten by refine's quantized output afterwards).
// chunk c within tile = ks*256 + sub*64 + row  (sub = k-octet, row = code 0..63)
#define TILE_U16 16384

// --------------- cb prep: exact c2 + tiled bf16 codebook (64 blocks) ----
__global__ __launch_bounds__(256) void vq_cbprep(const float* __restrict__ cb,
                                                 u16* __restrict__ ct,
                                                 float* __restrict__ c2) {
    const int b = blockIdx.x;        // 64 blocks: tile T = b>>2, part p = b&3
    const int T = b >> 2, p = b & 3;
    const int t = threadIdx.x, w = t >> 6, lane = t & 63;

    // c2 for 16 rows (exact fp32)
    #pragma unroll
    for (int i = 0; i < 4; ++i) {
        int g = T * 64 + p * 16 + i * 4 + w;
        float4 v = reinterpret_cast<const float4*>(cb)[(size_t)g * 64 + lane];
        float s = v.x * v.x + v.y * v.y + v.z * v.z + v.w * v.w;
        #pragma unroll
        for (int off = 32; off; off >>= 1) s += __shfl_xor(s, off);
        if (lane == 0) c2[g] = s;
    }

    // tiled bf16: this block covers chunks [p*512, p*512+512) of tile T
    #pragma unroll
    for (int i = 0; i < 2; ++i) {
        int c = p * 512 + i * 256 + t;
        int ks = c >> 8, sub = (c >> 6) & 3, row = c & 63;
        const float* src = cb + (size_t)(T * 64 + row) * 256 + ks * 32 + sub * 8;
        float4 a0 = *reinterpret_cast<const float4*>(src);
        float4 a1 = *reinterpret_cast<const float4*>(src + 4);
        bf16x8 v;
        v[0]=(__bf16)a0.x; v[1]=(__bf16)a0.y; v[2]=(__bf16)a0.z; v[3]=(__bf16)a0.w;
        v[4]=(__bf16)a1.x; v[5]=(__bf16)a1.y; v[6]=(__bf16)a1.z; v[7]=(__bf16)a1.w;
        *reinterpret_cast<bf16x8*>(ct + (size_t)T * TILE_U16 + (size_t)c * 8) = v;
    }
}

// ---- distance MFMA: A persistent in registers, B read DIRECTLY from L2
//      (no LDS, no barriers). 512 threads = 8 waves x 32 samples; block covers
//      256 samples x 256 codes. grid 512 = 128 sample-groups x 4 code-quarters:
//      exactly 2 blocks/CU, 16 waves/CU, one dispatch round.
__global__ __launch_bounds__(512, 2) void vq_dist(const float* __restrict__ x,
                                                  const u16* __restrict__ ct,
                                                  const float* __restrict__ c2,
                                                  float4* __restrict__ summ) {
    // XCD swizzle: each XCD owns 16 sample-groups x 4 code-quarters
    const int id = blockIdx.x;
    const int xcd = id & 7, r0 = id >> 3;          // r0 0..63
    const int sq = xcd * 16 + (r0 >> 2);           // 0..127
    const int cq = r0 & 3;                         // 0..3
    const int sBase = sq * 256;
    const int tile0 = cq * 4;

    const int t = threadIdx.x, w = t >> 6, lane = t & 63;   // w 0..7
    const int lo16 = lane & 15, hi = lane >> 4;

    // Load this wave's entire A-operand (32 samples x 256 k) into 64 VGPRs.
    const float* aw = x + (size_t)(sBase + w * 32) * 256;
    bf16x8 af[2][8];
    #pragma unroll
    for (int m = 0; m < 2; ++m) {
        #pragma unroll
        for (int ks = 0; ks < 8; ++ks) {
            const float* ap = aw + (size_t)(m * 16 + lo16) * 256 + ks * 32 + hi * 8;
            float4 a0 = *reinterpret_cast<const float4*>(ap);
            float4 a1 = *reinterpret_cast<const float4*>(ap + 4);
            bf16x8 v;
            v[0]=(__bf16)a0.x; v[1]=(__bf16)a0.y; v[2]=(__bf16)a0.z; v[3]=(__bf16)a0.w;
            v[4]=(__bf16)a1.x; v[5]=(__bf16)a1.y; v[6]=(__bf16)a1.z; v[7]=(__bf16)a1.w;
            af[m][ks] = v;
        }
    }

    for (int tt = 0; tt < 4; ++tt) {
        // per-lane base into the tiled codebook for this tile
        const bf16x8* bT = reinterpret_cast<const bf16x8*>(
            ct + (size_t)(tile0 + tt) * TILE_U16 + (size_t)(hi * 64 + lo16) * 8);

        f32x4 acc[2][4];
        #pragma unroll
        for (int m = 0; m < 2; ++m)
            #pragma unroll
            for (int n = 0; n < 4; ++n) acc[m][n] = (f32x4)0.f;

        #pragma unroll
        for (int ks = 0; ks < 8; ++ks) {
            bf16x8 bfr[4];
            #pragma unroll
            for (int n = 0; n < 4; ++n)
                bfr[n] = bT[ks * 256 + n * 16];      // coalesced 16B/lane from L2
            #pragma unroll
            for (int m = 0; m < 2; ++m)
                #pragma unroll
                for (int n = 0; n < 4; ++n)
                    acc[m][n] = __builtin_amdgcn_mfma_f32_16x16x32_bf16(af[m][ks], bfr[n], acc[m][n], 0, 0, 0);
        }

        // Epilogue for this 64-code tile: dd = c2 - 2*acc (x^2 cancels)
        const int cBase = (tile0 + tt) * 64;
        float c2v[4];
        #pragma unroll
        for (int j = 0; j < 4; ++j) c2v[j] = c2[cBase + j * 16 + lo16];

        #pragma unroll
        for (int m = 0; m < 2; ++m) {
            #pragma unroll
            for (int r = 0; r < 4; ++r) {
                const int R = sBase + w * 32 + m * 16 + hi * 4 + r;
                float dd[4];
                #pragma unroll
                for (int j = 0; j < 4; ++j) dd[j] = fmaf(-2.0f, acc[m][j][r], c2v[j]);
                float bm = fminf(fminf(dd[0], dd[1]), fminf(dd[2], dd[3]));
                #pragma unroll
                for (int off = 1; off < 16; off <<= 1) bm = fminf(bm, __shfl_xor(bm, off));
                const float thr = bm + TAU;
                u64 mk = 0ull;
                #pragma unroll
                for (int n = 0; n < 4; ++n) {
                    u64 b = __ballot(dd[n] < thr);
                    mk |= ((b >> (hi * 16)) & 0xFFFFull) << (n * 16);
                }
                if (lo16 == 0) {
                    float4 o;
                    o.x = bm;
                    o.y = 0.f;
                    o.z = __uint_as_float((unsigned)(mk & 0xFFFFFFFFull));
                    o.w = __uint_as_float((unsigned)(mk >> 32));
                    summ[(size_t)R * 16 + tile0 + tt] = o;
                }
            }
        }
    }
}

// ---------- exact fp32 refine, 4-way ILP, fused gather + histogram ----
__global__ __launch_bounds__(256) void vq_refine(const float* __restrict__ x,
                                                 const float* __restrict__ cb,
                                                 const float* __restrict__ c2,
                                                 const float4* __restrict__ summ,
                                                 float* __restrict__ hist,
                                                 float* __restrict__ pd,
                                                 float* __restrict__ ps,
                                                 float* __restrict__ outq,
                                                 float* __restrict__ out_idx_f) {
    __shared__ int   cd_k[4][128];
    __shared__ float cd_d[4][128];
    __shared__ float rd[4], rs[4];

    const int wid = threadIdx.x >> 6, lane = threadIdx.x & 63;
    const int s = blockIdx.x * 4 + wid;
    const float4 xv = reinterpret_cast<const float4*>(x)[(size_t)s * 64 + lane];

    // exact ||x_s||^2 (all lanes)
    float x2s = xv.x * xv.x + xv.y * xv.y + xv.z * xv.z + xv.w * xv.w;
    #pragma unroll
    for (int off = 32; off; off >>= 1) x2s += __shfl_xor(x2s, off);

    // parallel min over the 16 half-block summaries
    float gm = summ[(size_t)s * 16 + (lane & 15)].x;
    #pragma unroll
    for (int off = 1; off < 16; off <<= 1) gm = fminf(gm, __shfl_xor(gm, off));
    const float lim = gm + TAU;

    const float4* cb4 = reinterpret_cast<const float4*>(cb);
    float m = 3.4e38f, S1 = 0.f, S2 = 0.f;
    int bk = 0, cnt = 0;

    for (int hb = 0; hb < 16; ++hb) {
        float4 sm = summ[(size_t)s * 16 + hb];
        if (sm.x > lim) continue;
        u64 mk = ((u64)__float_as_uint(sm.w) << 32) | __float_as_uint(sm.z);
        while (mk) {
            // grab up to 4 candidates (wave-uniform walk; ascending k)
            int vc = 1;
            int b0 = __ffsll(mk) - 1; mk &= mk - 1;
            int k0 = hb * 64 + b0, k1 = k0, k2 = k0, k3 = k0;
            if (mk) { int b = __ffsll(mk) - 1; mk &= mk - 1; k1 = hb * 64 + b; vc = 2; }
            if (mk) { int b = __ffsll(mk) - 1; mk &= mk - 1; k2 = hb * 64 + b; vc = 3; }
            if (mk) { int b = __ffsll(mk) - 1; mk &= mk - 1; k3 = hb * 64 + b; vc = 4; }

            float4 cv0 = cb4[(size_t)k0 * 64 + lane];
            float4 cv1 = cb4[(size_t)k1 * 64 + lane];
            float4 cv2 = cb4[(size_t)k2 * 64 + lane];
            float4 cv3 = cb4[(size_t)k3 * 64 + lane];
            float r0 = xv.x*cv0.x + xv.y*cv0.y + xv.z*cv0.z + xv.w*cv0.w;
            float r1 = xv.x*cv1.x + xv.y*cv1.y + xv.z*cv1.z + xv.w*cv1.w;
            float r2 = xv.x*cv2.x + xv.y*cv2.y + xv.z*cv2.z + xv.w*cv2.w;
            float r3 = xv.x*cv3.x + xv.y*cv3.y + xv.z*cv3.z + xv.w*cv3.w;
            #pragma unroll
            for (int off = 32; off; off >>= 1) {
                r0 += __shfl_xor(r0, off);
                r1 += __shfl_xor(r1, off);
                r2 += __shfl_xor(r2, off);
                r3 += __shfl_xor(r3, off);
            }
            float dk[4];
            dk[0] = (x2s - 2.0f * r0) + c2[k0];
            dk[1] = (x2s - 2.0f * r1) + c2[k1];
            dk[2] = (x2s - 2.0f * r2) + c2[k2];
            dk[3] = (x2s - 2.0f * r3) + c2[k3];
            int kk[4] = {k0, k1, k2, k3};

            #pragma unroll
            for (int j = 0; j < 4; ++j) {
                if (j >= vc) break;
                float d = dk[j];
                if (lane == 0 && cnt < 128) { cd_k[wid][cnt] = kk[j]; cd_d[wid][cnt] = d; }
                ++cnt;
                if (S1 == 0.f)   { m = d; S1 = 1.f; S2 = 0.f; bk = kk[j]; }
                else if (d < m)  { float f = __expf((d - m) * INV_T);
                                   S2 = f * (S2 + (m - d) * S1);
                                   S1 = S1 * f + 1.f; m = d; bk = kk[j]; }
                else             { float e = __expf((m - d) * INV_T);
                                   S1 += e; S2 += e * (d - m); }
            }
        }
    }
    float sent = S2 * INV_T / S1 + logf(S1);
    if (lane == 0) { rd[wid] = m; rs[wid] = sent; }
    __syncthreads();

    // lane-parallel histogram update
    if (cnt > 128) cnt = 128;
    for (int c = lane; c < cnt; c += 64) {
        float dkv = cd_d[wid][c]; int k = cd_k[wid][c];
        atomicAdd(&hist[k], __expf((m - dkv) * INV_T) / S1);
    }

    // fused gather: quantized row = codebook[bk]
    reinterpret_cast<float4*>(outq)[(size_t)s * 64 + lane] = cb4[(size_t)bk * 64 + lane];
    if (lane == 0) out_idx_f[s] = (float)bk;

    if (threadIdx.x == 0) {
        pd[blockIdx.x] = rd[0] + rd[1] + rd[2] + rd[3];
        ps[blockIdx.x] = rs[0] + rs[1] + rs[2] + rs[3];
    }
}

// -------------------------------------------------------------- finalize ----
__global__ __launch_bounds__(256) void vq_finalize(const float* __restrict__ hist,
                                                   const float* __restrict__ pd,
                                                   const float* __restrict__ ps,
                                                   float* __restrict__ loss_out) {
    float ae = 0.f, sd = 0.f, se = 0.f;
    for (int k = threadIdx.x; k < KC; k += 256) {
        float p = hist[k] * (1.0f / (float)NS);
        ae += -p * logf(p + 1e-5f);
    }
    for (int b = threadIdx.x; b < 8192; b += 256) { sd += pd[b]; se += ps[b]; }
    #pragma unroll
    for (int off = 32; off; off >>= 1) {
        ae += __shfl_xor(ae, off); sd += __shfl_xor(sd, off); se += __shfl_xor(se, off);
    }
    __shared__ float r[3][4];
    int wid = threadIdx.x >> 6, lane = threadIdx.x & 63;
    if (lane == 0) { r[0][wid] = ae; r[1][wid] = sd; r[2][wid] = se; }
    __syncthreads();
    if (threadIdx.x == 0) {
        float AE = r[0][0] + r[0][1] + r[0][2] + r[0][3];
        float SD = r[1][0] + r[1][1] + r[1][2] + r[1][3];
        float SE = r[2][0] + r[2][1] + r[2][2] + r[2][3];
        float latent = 1.25f * SD / 8388608.0f;
        loss_out[0] = latent + 0.1f * (SE * (1.0f / (float)NS) - AE);
    }
}

extern "C" void kernel_launch(void* const* d_in, const int* in_sizes, int n_in,
                              void* d_out, int out_size, void* d_ws, size_t ws_size,
                              hipStream_t stream) {
    const float* x  = (const float*)d_in[0];
    const float* cb = (const float*)d_in[1];
    float* out = (float*)d_out;
    float* ws  = (float*)d_ws;

    // tiled bf16 codebook in first 512 KB of d_out (overwritten by refine later)
    u16* ct = (u16*)d_out;

    hipMemsetAsync(ws + HIST_OFF, 0, KC * sizeof(float), stream);

    vq_cbprep<<<64, 256, 0, stream>>>(cb, ct, ws + C2_OFF);
    vq_dist<<<512, 512, 0, stream>>>(x, ct, ws + C2_OFF, (float4*)(ws + SUMM_OFF));
    vq_refine<<<NS / 4, 256, 0, stream>>>(x, cb, ws + C2_OFF,
                                          (const float4*)(ws + SUMM_OFF),
                                          ws + HIST_OFF, ws + PD_OFF, ws + PS_OFF,
                                          out, out + 8388609);
    vq_finalize<<<1, 256, 0, stream>>>(ws + HIST_OFF, ws + PD_OFF, ws + PS_OFF,
                                       out + 8388608);
}

// Round 10
// 104.593 us; speedup vs baseline: 1.0933x; 1.0933x over previous
//
#include <hip/hip_runtime.h>
#include <math.h>

typedef unsigned short u16;
typedef unsigned long long u64;
typedef float    f32x4  __attribute__((ext_vector_type(4)));
typedef __bf16   bf16x8 __attribute__((ext_vector_type(8)));

#define NS    32768
#define KC    1024
#define INV_T 100.0f
#define TAU   2.0f

// ws layout (float offsets)
#define C2_OFF   0
#define SUMM_OFF 1024                      // [n][16 halfblocks] float4
#define SUMM_SZ  (NS * 16 * 4)
#define HIST_OFF (SUMM_OFF + SUMM_SZ)
#define PD_OFF   (HIST_OFF + KC)
#define PS_OFF   (PD_OFF + 8192)

// Fragment-chunk layouts (16B chunks of 8 bf16):
//  xb: 1024 tiles of 32 samples; chunk c = ks*128 + sub*32 + row   (8192 u16/tile)
//  ct: 16 tiles of 64 codes;     chunk c = ks*256 + sub*64 + row   (16384 u16/tile)
#define XTILE_U16 8192
#define TILE_U16  16384

__device__ __forceinline__ u16 f2bf(float f) {
    unsigned u = __float_as_uint(f);
    return (u16)((u + 0x7FFFu + ((u >> 16) & 1u)) >> 16);
}

__device__ __forceinline__ void gload_lds16(const void* g, void* l) {
    __builtin_amdgcn_global_load_lds((const __attribute__((address_space(1))) void*)g,
                                     (__attribute__((address_space(3))) void*)l, 16, 0, 0);
}

// --------------------- x fp32 -> bf16 fragment-chunk tiles (1024 blocks) ----
__global__ __launch_bounds__(256) void vq_xcvt(const float* __restrict__ x,
                                               u16* __restrict__ xb) {
    const int tl = blockIdx.x;            // 32-sample tile
    const int t = threadIdx.x;
    const float* src = x + (size_t)tl * 32 * 256;
    u16* dst = xb + (size_t)tl * XTILE_U16;
    #pragma unroll
    for (int j = 0; j < 4; ++j) {
        int row = j * 8 + (t >> 5);       // 0..31
        int kq0 = (t & 31) * 2;           // float4 index, step 2
        #pragma unroll
        for (int h = 0; h < 2; ++h) {
            int kq = kq0 + h;             // 0..63
            float4 v = reinterpret_cast<const float4*>(src)[(size_t)row * 64 + kq];
            int kk = kq * 4;              // element k 0..255
            int kss = kk >> 5;            // 32-k slice 0..7
            int sub = (kk >> 3) & 3;      // k-octet within slice
            int half = kq & 1;            // half of the 8-elem chunk
            ushort4 o;
            o.x = f2bf(v.x); o.y = f2bf(v.y); o.z = f2bf(v.z); o.w = f2bf(v.w);
            *reinterpret_cast<ushort4*>(
                dst + ((size_t)kss * 128 + sub * 32 + row) * 8 + half * 4) = o;
        }
    }
}

// --------------- cb prep: exact c2 + tiled bf16 codebook (64 blocks) ----
__global__ __launch_bounds__(256) void vq_cbprep(const float* __restrict__ cb,
                                                 u16* __restrict__ ct,
                                                 float* __restrict__ c2) {
    const int b = blockIdx.x;        // 64 blocks: tile T = b>>2, part p = b&3
    const int T = b >> 2, p = b & 3;
    const int t = threadIdx.x, w = t >> 6, lane = t & 63;

    #pragma unroll
    for (int i = 0; i < 4; ++i) {
        int g = T * 64 + p * 16 + i * 4 + w;
        float4 v = reinterpret_cast<const float4*>(cb)[(size_t)g * 64 + lane];
        float s = v.x * v.x + v.y * v.y + v.z * v.z + v.w * v.w;
        #pragma unroll
        for (int off = 32; off; off >>= 1) s += __shfl_xor(s, off);
        if (lane == 0) c2[g] = s;
    }

    #pragma unroll
    for (int i = 0; i < 2; ++i) {
        int c = p * 512 + i * 256 + t;
        int ks = c >> 8, sub = (c >> 6) & 3, row = c & 63;
        const float* srcp = cb + (size_t)(T * 64 + row) * 256 + ks * 32 + sub * 8;
        float4 a0 = *reinterpret_cast<const float4*>(srcp);
        float4 a1 = *reinterpret_cast<const float4*>(srcp + 4);
        bf16x8 v;
        v[0]=(__bf16)a0.x; v[1]=(__bf16)a0.y; v[2]=(__bf16)a0.z; v[3]=(__bf16)a0.w;
        v[4]=(__bf16)a1.x; v[5]=(__bf16)a1.y; v[6]=(__bf16)a1.z; v[7]=(__bf16)a1.w;
        *reinterpret_cast<bf16x8*>(ct + (size_t)T * TILE_U16 + (size_t)c * 8) = v;
    }
}

// ---- distance MFMA: B in LDS once (no loop barriers), A bf16 reg-dbuf
//      streamed over the LONG sample axis. grid 512 = 16 code-tiles x 32
//      sample-groups (1024 samples); 4 waves x 32 samples/chunk, 8 chunks.
__global__ __launch_bounds__(256, 2) void vq_dist(const u16* __restrict__ xb,
                                                  const u16* __restrict__ ct,
                                                  const float* __restrict__ c2,
                                                  float4* __restrict__ summ) {
    __shared__ __align__(16) u16 Bs[TILE_U16];   // 32 KB, staged once

    // XCD swizzle: the 16 code-tile blocks of one sample-group share an XCD
    const int id = blockIdx.x;
    const int xcd = id & 7, j = id >> 3;         // j 0..63
    const int bx = j >> 2;                       // code tile 0..15
    const int sg = xcd * 4 + (j & 3);            // sample group 0..31
    const int cBase = bx * 64;

    const int t = threadIdx.x, w = t >> 6, lane = t & 63;
    const int lo16 = lane & 15, hi = lane >> 4;

    // stage the 64-code B tile (once)
    {
        const u16* bT = ct + (size_t)bx * TILE_U16;
        #pragma unroll
        for (int i = 0; i < 8; ++i) {
            int c0 = (i * 4 + w) * 64;
            gload_lds16(bT + (size_t)(c0 + lane) * 8, &Bs[c0 * 8]);
        }
    }

    #define LOAD_AF(DST, IT)                                                       \
        do {                                                                       \
            const u16* aT_ = xb + (size_t)(sg * 32 + (IT) * 4 + w) * XTILE_U16;    \
            _Pragma("unroll")                                                      \
            for (int m_ = 0; m_ < 2; ++m_)                                         \
                _Pragma("unroll")                                                  \
                for (int ks_ = 0; ks_ < 8; ++ks_)                                  \
                    DST[m_][ks_] = *reinterpret_cast<const bf16x8*>(               \
                        aT_ + ((size_t)ks_ * 128 + hi * 32 + m_ * 16 + lo16) * 8); \
        } while (0)

    float c2v[4];
    #pragma unroll
    for (int n = 0; n < 4; ++n) c2v[n] = c2[cBase + n * 16 + lo16];

    bf16x8 afA[2][8], afB[2][8];
    LOAD_AF(afA, 0);
    __syncthreads();     // B tile ready

    #define COMPUTE(AF, IT)                                                        \
        do {                                                                       \
            f32x4 acc[2][4];                                                       \
            _Pragma("unroll")                                                      \
            for (int m_ = 0; m_ < 2; ++m_)                                         \
                _Pragma("unroll")                                                  \
                for (int n_ = 0; n_ < 4; ++n_) acc[m_][n_] = (f32x4)0.f;           \
            _Pragma("unroll")                                                      \
            for (int ks_ = 0; ks_ < 8; ++ks_) {                                    \
                bf16x8 bfr[4];                                                     \
                _Pragma("unroll")                                                  \
                for (int n_ = 0; n_ < 4; ++n_)                                     \
                    bfr[n_] = *reinterpret_cast<const bf16x8*>(                    \
                        &Bs[((size_t)ks_ * 256 + hi * 64 + n_ * 16 + lo16) * 8]);  \
                _Pragma("unroll")                                                  \
                for (int m_ = 0; m_ < 2; ++m_)                                     \
                    _Pragma("unroll")                                              \
                    for (int n_ = 0; n_ < 4; ++n_)                                 \
                        acc[m_][n_] = __builtin_amdgcn_mfma_f32_16x16x32_bf16(     \
                            AF[m_][ks_], bfr[n_], acc[m_][n_], 0, 0, 0);           \
            }                                                                      \
            _Pragma("unroll")                                                      \
            for (int m_ = 0; m_ < 2; ++m_) {                                       \
                _Pragma("unroll")                                                  \
                for (int r_ = 0; r_ < 4; ++r_) {                                   \
                    const int R = sg * 1024 + (IT) * 128 + w * 32                  \
                                  + m_ * 16 + hi * 4 + r_;                         \
                    float dd[4];                                                   \
                    _Pragma("unroll")                                              \
                    for (int n_ = 0; n_ < 4; ++n_)                                 \
                        dd[n_] = fmaf(-2.0f, acc[m_][n_][r_], c2v[n_]);            \
                    float bm = fminf(fminf(dd[0], dd[1]), fminf(dd[2], dd[3]));    \
                    _Pragma("unroll")                                              \
                    for (int off_ = 1; off_ < 16; off_ <<= 1)                      \
                        bm = fminf(bm, __shfl_xor(bm, off_));                      \
                    const float thr = bm + TAU;                                    \
                    u64 mk = 0ull;                                                 \
                    _Pragma("unroll")                                              \
                    for (int n_ = 0; n_ < 4; ++n_) {                               \
                        u64 bb = __ballot(dd[n_] < thr);                           \
                        mk |= ((bb >> (hi * 16)) & 0xFFFFull) << (n_ * 16);        \
                    }                                                              \
                    if (lo16 == 0) {                                               \
                        float4 o;                                                  \
                        o.x = bm;                                                  \
                        o.y = 0.f;                                                 \
                        o.z = __uint_as_float((unsigned)(mk & 0xFFFFFFFFull));     \
                        o.w = __uint_as_float((unsigned)(mk >> 32));               \
                        summ[(size_t)R * 16 + bx] = o;                             \
                    }                                                              \
                }                                                                  \
            }                                                                      \
        } while (0)

    // 8 chunks, hand-unrolled pairs: loads for i+1 issue before compute of i.
    #pragma unroll
    for (int itp = 0; itp < 4; ++itp) {
        const int it = itp * 2;
        LOAD_AF(afB, it + 1);
        COMPUTE(afA, it);
        if (itp < 3) LOAD_AF(afA, it + 2);
        COMPUTE(afB, it + 1);
    }
    #undef LOAD_AF
    #undef COMPUTE
}

// ---------- exact fp32 refine, 4-way ILP, fused gather + histogram ----
__global__ __launch_bounds__(256) void vq_refine(const float* __restrict__ x,
                                                 const float* __restrict__ cb,
                                                 const float* __restrict__ c2,
                                                 const float4* __restrict__ summ,
                                                 float* __restrict__ hist,
                                                 float* __restrict__ pd,
                                                 float* __restrict__ ps,
                                                 float* __restrict__ outq,
                                                 float* __restrict__ out_idx_f) {
    __shared__ int   cd_k[4][128];
    __shared__ float cd_d[4][128];
    __shared__ float rd[4], rs[4];

    const int wid = threadIdx.x >> 6, lane = threadIdx.x & 63;
    const int s = blockIdx.x * 4 + wid;
    const float4 xv = reinterpret_cast<const float4*>(x)[(size_t)s * 64 + lane];

    float x2s = xv.x * xv.x + xv.y * xv.y + xv.z * xv.z + xv.w * xv.w;
    #pragma unroll
    for (int off = 32; off; off >>= 1) x2s += __shfl_xor(x2s, off);

    float gm = summ[(size_t)s * 16 + (lane & 15)].x;
    #pragma unroll
    for (int off = 1; off < 16; off <<= 1) gm = fminf(gm, __shfl_xor(gm, off));
    const float lim = gm + TAU;

    const float4* cb4 = reinterpret_cast<const float4*>(cb);
    float m = 3.4e38f, S1 = 0.f, S2 = 0.f;
    int bk = 0, cnt = 0;

    for (int hb = 0; hb < 16; ++hb) {
        float4 sm = summ[(size_t)s * 16 + hb];
        if (sm.x > lim) continue;
        u64 mk = ((u64)__float_as_uint(sm.w) << 32) | __float_as_uint(sm.z);
        while (mk) {
            int vc = 1;
            int b0 = __ffsll(mk) - 1; mk &= mk - 1;
            int k0 = hb * 64 + b0, k1 = k0, k2 = k0, k3 = k0;
            if (mk) { int b = __ffsll(mk) - 1; mk &= mk - 1; k1 = hb * 64 + b; vc = 2; }
            if (mk) { int b = __ffsll(mk) - 1; mk &= mk - 1; k2 = hb * 64 + b; vc = 3; }
            if (mk) { int b = __ffsll(mk) - 1; mk &= mk - 1; k3 = hb * 64 + b; vc = 4; }

            float4 cv0 = cb4[(size_t)k0 * 64 + lane];
            float4 cv1 = cb4[(size_t)k1 * 64 + lane];
            float4 cv2 = cb4[(size_t)k2 * 64 + lane];
            float4 cv3 = cb4[(size_t)k3 * 64 + lane];
            float r0 = xv.x*cv0.x + xv.y*cv0.y + xv.z*cv0.z + xv.w*cv0.w;
            float r1 = xv.x*cv1.x + xv.y*cv1.y + xv.z*cv1.z + xv.w*cv1.w;
            float r2 = xv.x*cv2.x + xv.y*cv2.y + xv.z*cv2.z + xv.w*cv2.w;
            float r3 = xv.x*cv3.x + xv.y*cv3.y + xv.z*cv3.z + xv.w*cv3.w;
            #pragma unroll
            for (int off = 32; off; off >>= 1) {
                r0 += __shfl_xor(r0, off);
                r1 += __shfl_xor(r1, off);
                r2 += __shfl_xor(r2, off);
                r3 += __shfl_xor(r3, off);
            }
            float dk[4];
            dk[0] = (x2s - 2.0f * r0) + c2[k0];
            dk[1] = (x2s - 2.0f * r1) + c2[k1];
            dk[2] = (x2s - 2.0f * r2) + c2[k2];
            dk[3] = (x2s - 2.0f * r3) + c2[k3];
            int kk[4] = {k0, k1, k2, k3};

            #pragma unroll
            for (int jj = 0; jj < 4; ++jj) {
                if (jj >= vc) break;
                float d = dk[jj];
                if (lane == 0 && cnt < 128) { cd_k[wid][cnt] = kk[jj]; cd_d[wid][cnt] = d; }
                ++cnt;
                if (S1 == 0.f)   { m = d; S1 = 1.f; S2 = 0.f; bk = kk[jj]; }
                else if (d < m)  { float f = __expf((d - m) * INV_T);
                                   S2 = f * (S2 + (m - d) * S1);
                                   S1 = S1 * f + 1.f; m = d; bk = kk[jj]; }
                else             { float e = __expf((m - d) * INV_T);
                                   S1 += e; S2 += e * (d - m); }
            }
        }
    }
    float sent = S2 * INV_T / S1 + logf(S1);
    if (lane == 0) { rd[wid] = m; rs[wid] = sent; }
    __syncthreads();

    if (cnt > 128) cnt = 128;
    for (int c = lane; c < cnt; c += 64) {
        float dkv = cd_d[wid][c]; int k = cd_k[wid][c];
        atomicAdd(&hist[k], __expf((m - dkv) * INV_T) / S1);
    }

    reinterpret_cast<float4*>(outq)[(size_t)s * 64 + lane] = cb4[(size_t)bk * 64 + lane];
    if (lane == 0) out_idx_f[s] = (float)bk;

    if (threadIdx.x == 0) {
        pd[blockIdx.x] = rd[0] + rd[1] + rd[2] + rd[3];
        ps[blockIdx.x] = rs[0] + rs[1] + rs[2] + rs[3];
    }
}

// -------------------------------------------------------------- finalize ----
__global__ __launch_bounds__(256) void vq_finalize(const float* __restrict__ hist,
                                                   const float* __restrict__ pd,
                                                   const float* __restrict__ ps,
                                                   float* __restrict__ loss_out) {
    float ae = 0.f, sd = 0.f, se = 0.f;
    for (int k = threadIdx.x; k < KC; k += 256) {
        float p = hist[k] * (1.0f / (float)NS);
        ae += -p * logf(p + 1e-5f);
    }
    for (int b = threadIdx.x; b < 8192; b += 256) { sd += pd[b]; se += ps[b]; }
    #pragma unroll
    for (int off = 32; off; off >>= 1) {
        ae += __shfl_xor(ae, off); sd += __shfl_xor(sd, off); se += __shfl_xor(se, off);
    }
    __shared__ float r[3][4];
    int wid = threadIdx.x >> 6, lane = threadIdx.x & 63;
    if (lane == 0) { r[0][wid] = ae; r[1][wid] = sd; r[2][wid] = se; }
    __syncthreads();
    if (threadIdx.x == 0) {
        float AE = r[0][0] + r[0][1] + r[0][2] + r[0][3];
        float SD = r[1][0] + r[1][1] + r[1][2] + r[1][3];
        float SE = r[2][0] + r[2][1] + r[2][2] + r[2][3];
        float latent = 1.25f * SD / 8388608.0f;
        loss_out[0] = latent + 0.1f * (SE * (1.0f / (float)NS) - AE);
    }
}

extern "C" void kernel_launch(void* const* d_in, const int* in_sizes, int n_in,
                              void* d_out, int out_size, void* d_ws, size_t ws_size,
                              hipStream_t stream) {
    const float* x  = (const float*)d_in[0];
    const float* cb = (const float*)d_in[1];
    float* out = (float*)d_out;
    float* ws  = (float*)d_ws;

    // bf16 scratch in d_out's quantized region (overwritten by refine later):
    u16* xb = (u16*)d_out;                       // 16 MB (floats 0..4M)
    u16* ct = (u16*)(out + 4194304);             // 512 KB

    hipMemsetAsync(ws + HIST_OFF, 0, KC * sizeof(float), stream);

    vq_xcvt<<<1024, 256, 0, stream>>>(x, xb);
    vq_cbprep<<<64, 256, 0, stream>>>(cb, ct, ws + C2_OFF);
    vq_dist<<<512, 256, 0, stream>>>(xb, ct, ws + C2_OFF, (float4*)(ws + SUMM_OFF));
    vq_refine<<<NS / 4, 256, 0, stream>>>(x, cb, ws + C2_OFF,
                                          (const float4*)(ws + SUMM_OFF),
                                          ws + HIST_OFF, ws + PD_OFF, ws + PS_OFF,
                                          out, out + 8388609);
    vq_finalize<<<1, 256, 0, stream>>>(ws + HIST_OFF, ws + PD_OFF, ws + PS_OFF,
                                       out + 8388608);
}

// Round 12
// 104.585 us; speedup vs baseline: 1.0933x; 1.0001x over previous
//
#include <hip/hip_runtime.h>
#include <math.h>

typedef unsigned short u16;
typedef unsigned int u32;
typedef unsigned long long u64;
typedef float    f32x4  __attribute__((ext_vector_type(4)));
typedef __bf16   bf16x8 __attribute__((ext_vector_type(8)));

#define NS    32768
#define KC    1024
#define INV_T 100.0f
#define TAU   2.0f

// ws layout (float offsets)
#define C2_OFF   0
#define SUMM_OFF 1024                      // [n][32 blocks] float2 = 8 MB
#define SUMM_SZ  (NS * 32 * 2)
#define HIST_OFF (SUMM_OFF + SUMM_SZ)
#define PD_OFF   (HIST_OFF + KC)
#define PS_OFF   (PD_OFF + 8192)

// Fragment-chunk layouts (16B chunks of 8 bf16):
//  xb: 1024 tiles of 32 samples; chunk = ks*128 + sub*32 + row   (8192 u16/tile)
//  ct: 32 tiles of 32 codes;     chunk = ks*128 + sub*32 + row   (8192 u16/tile)
#define XTILE_U16 8192
#define CTILE_U16 8192

__device__ __forceinline__ u16 f2bf(float f) {
    unsigned u = __float_as_uint(f);
    return (u16)((u + 0x7FFFu + ((u >> 16) & 1u)) >> 16);
}

__device__ __forceinline__ void gload_lds16(const void* g, void* l) {
    __builtin_amdgcn_global_load_lds((const __attribute__((address_space(1))) void*)g,
                                     (__attribute__((address_space(3))) void*)l, 16, 0, 0);
}

// --------------------- x fp32 -> bf16 fragment-chunk tiles (1024 blocks) ----
__global__ __launch_bounds__(256) void vq_xcvt(const float* __restrict__ x,
                                               u16* __restrict__ xb) {
    const int tl = blockIdx.x;            // 32-sample tile
    const int t = threadIdx.x;
    const float* src = x + (size_t)tl * 32 * 256;
    u16* dst = xb + (size_t)tl * XTILE_U16;
    #pragma unroll
    for (int j = 0; j < 4; ++j) {
        int row = j * 8 + (t >> 5);       // 0..31
        int kq0 = (t & 31) * 2;           // float4 index, step 2
        #pragma unroll
        for (int h = 0; h < 2; ++h) {
            int kq = kq0 + h;             // 0..63
            float4 v = reinterpret_cast<const float4*>(src)[(size_t)row * 64 + kq];
            int kk = kq * 4;
            int kss = kk >> 5;            // 32-k slice 0..7
            int sub = (kk >> 3) & 3;      // k-octet within slice
            int half = kq & 1;
            ushort4 o;
            o.x = f2bf(v.x); o.y = f2bf(v.y); o.z = f2bf(v.z); o.w = f2bf(v.w);
            *reinterpret_cast<ushort4*>(
                dst + ((size_t)kss * 128 + sub * 32 + row) * 8 + half * 4) = o;
        }
    }
}

// --------------- cb prep: exact c2 + tiled bf16 codebook (64 blocks) ----
__global__ __launch_bounds__(256) void vq_cbprep(const float* __restrict__ cb,
                                                 u16* __restrict__ ct,
                                                 float* __restrict__ c2) {
    const int b = blockIdx.x;        // 64 blocks
    const int t = threadIdx.x, w = t >> 6, lane = t & 63;

    // c2 for 16 codes (exact fp32)
    #pragma unroll
    for (int i = 0; i < 4; ++i) {
        int g = b * 16 + i * 4 + w;
        float4 v = reinterpret_cast<const float4*>(cb)[(size_t)g * 64 + lane];
        float s = v.x * v.x + v.y * v.y + v.z * v.z + v.w * v.w;
        #pragma unroll
        for (int off = 32; off; off >>= 1) s += __shfl_xor(s, off);
        if (lane == 0) c2[g] = s;
    }

    // tiled bf16: tile T = b>>1 (32 codes), part p = b&1 -> chunks [p*512, p*512+512)
    const int T = b >> 1, p = b & 1;
    #pragma unroll
    for (int i = 0; i < 2; ++i) {
        int c = p * 512 + i * 256 + t;            // chunk 0..1023
        int ks = c >> 7, sub = (c >> 5) & 3, row = c & 31;
        const float* srcp = cb + (size_t)(T * 32 + row) * 256 + ks * 32 + sub * 8;
        float4 a0 = *reinterpret_cast<const float4*>(srcp);
        float4 a1 = *reinterpret_cast<const float4*>(srcp + 4);
        bf16x8 v;
        v[0]=(__bf16)a0.x; v[1]=(__bf16)a0.y; v[2]=(__bf16)a0.z; v[3]=(__bf16)a0.w;
        v[4]=(__bf16)a1.x; v[5]=(__bf16)a1.y; v[6]=(__bf16)a1.z; v[7]=(__bf16)a1.w;
        *reinterpret_cast<bf16x8*>(ct + (size_t)T * CTILE_U16 + (size_t)c * 8) = v;
    }
}

// ---- distance MFMA: swapped operands (codes=rows, samples=cols).
//      A (32 samples/wave) persistent in regs; B = 32-code tiles dbuf via LDS
//      (2x16KB). grid 1024 = 256 sample-groups x 4 quarters; 4 blocks/CU.
__global__ __launch_bounds__(256, 4) void vq_dist(const u16* __restrict__ xb,
                                                  const u16* __restrict__ ct,
                                                  const float* __restrict__ c2,
                                                  float2* __restrict__ summ) {
    __shared__ __align__(16) u16 Bs[2][CTILE_U16];   // 2 x 16 KB

    // XCD swizzle: each XCD owns 32 sample-groups x 4 quarters
    const int id = blockIdx.x;
    const int xcd = id & 7, j = id >> 3;         // j 0..127
    const int sq = xcd * 32 + (j >> 2);          // sample group 0..255 (128 samples)
    const int q  = j & 3;                        // code quarter 0..3
    const int sBase = sq * 128;

    const int t = threadIdx.x, w = t >> 6, lane = t & 63;
    const int lo16 = lane & 15, hi = lane >> 4;
    const int hi4 = hi * 4;

    #define STAGE(buf, bt)                                                        \
        do {                                                                      \
            const u16* bT_ = ct + (size_t)(bt) * CTILE_U16;                       \
            _Pragma("unroll")                                                     \
            for (int i_ = 0; i_ < 4; ++i_) {                                      \
                int c0_ = (i_ * 4 + w) * 64;                                      \
                gload_lds16(bT_ + (size_t)(c0_ + lane) * 8, &Bs[buf][c0_ * 8]);   \
            }                                                                     \
        } while (0)

    STAGE(0, q * 8);

    // A-operand: 32 samples x 256 k, persistent (64 regs)
    const u16* aT = xb + (size_t)(sq * 4 + w) * XTILE_U16;
    bf16x8 af[2][8];
    #pragma unroll
    for (int sm = 0; sm < 2; ++sm)
        #pragma unroll
        for (int ks = 0; ks < 8; ++ks)
            af[sm][ks] = *reinterpret_cast<const bf16x8*>(
                aT + ((size_t)ks * 128 + hi * 32 + sm * 16 + lo16) * 8);
    __syncthreads();

    int cur = 0;
    for (int tt = 0; tt < 8; ++tt) {
        if (tt < 7) STAGE(cur ^ 1, q * 8 + tt + 1);

        f32x4 acc[2][2];                 // [code-group cn][sample-group sm]
        #pragma unroll
        for (int cn = 0; cn < 2; ++cn)
            #pragma unroll
            for (int sm = 0; sm < 2; ++sm) acc[cn][sm] = (f32x4)0.f;

        const u16* bsc = &Bs[cur][0];
        #pragma unroll
        for (int ks = 0; ks < 8; ++ks) {
            bf16x8 bfr[2];
            #pragma unroll
            for (int cn = 0; cn < 2; ++cn)
                bfr[cn] = *reinterpret_cast<const bf16x8*>(
                    &bsc[((size_t)ks * 128 + hi * 32 + cn * 16 + lo16) * 8]);
            #pragma unroll
            for (int cn = 0; cn < 2; ++cn)
                #pragma unroll
                for (int sm = 0; sm < 2; ++sm)
                    acc[cn][sm] = __builtin_amdgcn_mfma_f32_16x16x32_bf16(
                        bfr[cn], af[sm][ks], acc[cn][sm], 0, 0, 0);
        }

        // Epilogue: lane owns sample (sm*16+lo16) x codes (cn*16 + hi4 + r).
        const int cBase = q * 256 + tt * 32;
        float c2v[2][4];
        #pragma unroll
        for (int cn = 0; cn < 2; ++cn)
            #pragma unroll
            for (int r = 0; r < 4; ++r)
                c2v[cn][r] = c2[cBase + cn * 16 + hi4 + r];

        #pragma unroll
        for (int sm = 0; sm < 2; ++sm) {
            float dd[2][4];
            #pragma unroll
            for (int cn = 0; cn < 2; ++cn)
                #pragma unroll
                for (int r = 0; r < 4; ++r)
                    dd[cn][r] = fmaf(-2.0f, acc[cn][sm][r], c2v[cn][r]);
            // in-register min over 8 codes
            float bm = dd[0][0];
            #pragma unroll
            for (int cn = 0; cn < 2; ++cn)
                #pragma unroll
                for (int r = 0; r < 4; ++r) bm = fminf(bm, dd[cn][r]);
            // cross-hi min (2 shfls; lanes share lo16)
            bm = fminf(bm, __shfl_xor(bm, 16));
            bm = fminf(bm, __shfl_xor(bm, 32));
            const float thr = bm + TAU;
            // local 32-bit mask: bit cn*16 + hi4 + r
            u32 m32 = 0;
            #pragma unroll
            for (int cn = 0; cn < 2; ++cn)
                #pragma unroll
                for (int r = 0; r < 4; ++r)
                    m32 |= (dd[cn][r] < thr ? 1u : 0u) << (cn * 16 + hi4 + r);
            m32 |= __shfl_xor(m32, 16);
            m32 |= __shfl_xor(m32, 32);
            if (hi == 0) {
                const int R = sBase + w * 32 + sm * 16 + lo16;
                float2 o; o.x = bm; o.y = __uint_as_float(m32);
                summ[(size_t)R * 32 + q * 8 + tt] = o;
            }
        }
        __syncthreads();
        cur ^= 1;
    }
    #undef STAGE
}

// ---------- exact fp32 refine, 4-way ILP, fused gather + histogram ----
__global__ __launch_bounds__(256) void vq_refine(const float* __restrict__ x,
                                                 const float* __restrict__ cb,
                                                 const float* __restrict__ c2,
                                                 const float2* __restrict__ summ,
                                                 float* __restrict__ hist,
                                                 float* __restrict__ pd,
                                                 float* __restrict__ ps,
                                                 float* __restrict__ outq,
                                                 float* __restrict__ out_idx_f) {
    __shared__ int   cd_k[4][128];
    __shared__ float cd_d[4][128];
    __shared__ float rd[4], rs[4];

    const int wid = threadIdx.x >> 6, lane = threadIdx.x & 63;
    const int s = blockIdx.x * 4 + wid;
    const float4 xv = reinterpret_cast<const float4*>(x)[(size_t)s * 64 + lane];

    float x2s = xv.x * xv.x + xv.y * xv.y + xv.z * xv.z + xv.w * xv.w;
    #pragma unroll
    for (int off = 32; off; off >>= 1) x2s += __shfl_xor(x2s, off);

    // parallel min over the 32 block summaries
    float gm = summ[(size_t)s * 32 + (lane & 31)].x;
    #pragma unroll
    for (int off = 1; off < 32; off <<= 1) gm = fminf(gm, __shfl_xor(gm, off));
    const float lim = gm + TAU;

    const float4* cb4 = reinterpret_cast<const float4*>(cb);
    float m = 3.4e38f, S1 = 0.f, S2 = 0.f;
    int bk = 0, cnt = 0;

    for (int hb = 0; hb < 32; ++hb) {
        float2 sm = summ[(size_t)s * 32 + hb];
        if (sm.x > lim) continue;
        u32 mk = __float_as_uint(sm.y);
        while (mk) {
            int vc = 1;
            int b0 = __ffs(mk) - 1; mk &= mk - 1;
            int k0 = hb * 32 + b0, k1 = k0, k2 = k0, k3 = k0;
            if (mk) { int b = __ffs(mk) - 1; mk &= mk - 1; k1 = hb * 32 + b; vc = 2; }
            if (mk) { int b = __ffs(mk) - 1; mk &= mk - 1; k2 = hb * 32 + b; vc = 3; }
            if (mk) { int b = __ffs(mk) - 1; mk &= mk - 1; k3 = hb * 32 + b; vc = 4; }

            float4 cv0 = cb4[(size_t)k0 * 64 + lane];
            float4 cv1 = cb4[(size_t)k1 * 64 + lane];
            float4 cv2 = cb4[(size_t)k2 * 64 + lane];
            float4 cv3 = cb4[(size_t)k3 * 64 + lane];
            float r0 = xv.x*cv0.x + xv.y*cv0.y + xv.z*cv0.z + xv.w*cv0.w;
            float r1 = xv.x*cv1.x + xv.y*cv1.y + xv.z*cv1.z + xv.w*cv1.w;
            float r2 = xv.x*cv2.x + xv.y*cv2.y + xv.z*cv2.z + xv.w*cv2.w;
            float r3 = xv.x*cv3.x + xv.y*cv3.y + xv.z*cv3.z + xv.w*cv3.w;
            #pragma unroll
            for (int off = 32; off; off >>= 1) {
                r0 += __shfl_xor(r0, off);
                r1 += __shfl_xor(r1, off);
                r2 += __shfl_xor(r2, off);
                r3 += __shfl_xor(r3, off);
            }
            float dk[4];
            dk[0] = (x2s - 2.0f * r0) + c2[k0];
            dk[1] = (x2s - 2.0f * r1) + c2[k1];
            dk[2] = (x2s - 2.0f * r2) + c2[k2];
            dk[3] = (x2s - 2.0f * r3) + c2[k3];
            int kk[4] = {k0, k1, k2, k3};

            #pragma unroll
            for (int jj = 0; jj < 4; ++jj) {
                if (jj >= vc) break;
                float d = dk[jj];
                if (lane == 0 && cnt < 128) { cd_k[wid][cnt] = kk[jj]; cd_d[wid][cnt] = d; }
                ++cnt;
                if (S1 == 0.f)   { m = d; S1 = 1.f; S2 = 0.f; bk = kk[jj]; }
                else if (d < m)  { float f = __expf((d - m) * INV_T);
                                   S2 = f * (S2 + (m - d) * S1);
                                   S1 = S1 * f + 1.f; m = d; bk = kk[jj]; }
                else             { float e = __expf((m - d) * INV_T);
                                   S1 += e; S2 += e * (d - m); }
            }
        }
    }
    float sent = S2 * INV_T / S1 + logf(S1);
    if (lane == 0) { rd[wid] = m; rs[wid] = sent; }
    __syncthreads();

    if (cnt > 128) cnt = 128;
    for (int c = lane; c < cnt; c += 64) {
        float dkv = cd_d[wid][c]; int k = cd_k[wid][c];
        atomicAdd(&hist[k], __expf((m - dkv) * INV_T) / S1);
    }

    reinterpret_cast<float4*>(outq)[(size_t)s * 64 + lane] = cb4[(size_t)bk * 64 + lane];
    if (lane == 0) out_idx_f[s] = (float)bk;

    if (threadIdx.x == 0) {
        pd[blockIdx.x] = rd[0] + rd[1] + rd[2] + rd[3];
        ps[blockIdx.x] = rs[0] + rs[1] + rs[2] + rs[3];
    }
}

// -------------------------------------------------------------- finalize ----
__global__ __launch_bounds__(256) void vq_finalize(const float* __restrict__ hist,
                                                   const float* __restrict__ pd,
                                                   const float* __restrict__ ps,
                                                   float* __restrict__ loss_out) {
    float ae = 0.f, sd = 0.f, se = 0.f;
    for (int k = threadIdx.x; k < KC; k += 256) {
        float p = hist[k] * (1.0f / (float)NS);
        ae += -p * logf(p + 1e-5f);
    }
    for (int b = threadIdx.x; b < 8192; b += 256) { sd += pd[b]; se += ps[b]; }
    #pragma unroll
    for (int off = 32; off; off >>= 1) {
        ae += __shfl_xor(ae, off); sd += __shfl_xor(sd, off); se += __shfl_xor(se, off);
    }
    __shared__ float r[3][4];
    int wid = threadIdx.x >> 6, lane = threadIdx.x & 63;
    if (lane == 0) { r[0][wid] = ae; r[1][wid] = sd; r[2][wid] = se; }
    __syncthreads();
    if (threadIdx.x == 0) {
        float AE = r[0][0] + r[0][1] + r[0][2] + r[0][3];
        float SD = r[1][0] + r[1][1] + r[1][2] + r[1][3];
        float SE = r[2][0] + r[2][1] + r[2][2] + r[2][3];
        float latent = 1.25f * SD / 8388608.0f;
        loss_out[0] = latent + 0.1f * (SE * (1.0f / (float)NS) - AE);
    }
}

extern "C" void kernel_launch(void* const* d_in, const int* in_sizes, int n_in,
                              void* d_out, int out_size, void* d_ws, size_t ws_size,
                              hipStream_t stream) {
    const float* x  = (const float*)d_in[0];
    const float* cb = (const float*)d_in[1];
    float* out = (float*)d_out;
    float* ws  = (float*)d_ws;

    // bf16 scratch in d_out's quantized region (overwritten by refine later):
    u16* xb = (u16*)d_out;                       // 16 MB
    u16* ct = (u16*)(out + 4194304);             // 512 KB

    hipMemsetAsync(ws + HIST_OFF, 0, KC * sizeof(float), stream);

    vq_xcvt<<<1024, 256, 0, stream>>>(x, xb);
    vq_cbprep<<<64, 256, 0, stream>>>(cb, ct, ws + C2_OFF);
    vq_dist<<<1024, 256, 0, stream>>>(xb, ct, ws + C2_OFF, (float2*)(ws + SUMM_OFF));
    vq_refine<<<NS / 4, 256, 0, stream>>>(x, cb, ws + C2_OFF,
                                          (const float2*)(ws + SUMM_OFF),
                                          ws + HIST_OFF, ws + PD_OFF, ws + PS_OFF,
                                          out, out + 8388609);
    vq_finalize<<<1, 256, 0, stream>>>(ws + HIST_OFF, ws + PD_OFF, ws + PS_OFF,
                                       out + 8388608);
}

// Round 13
// 92.633 us; speedup vs baseline: 1.2344x; 1.1290x over previous
//
#include <hip/hip_runtime.h>
#include <math.h>

typedef unsigned short u16;
typedef unsigned int u32;
typedef unsigned long long u64;
typedef float    f32x4  __attribute__((ext_vector_type(4)));
typedef __bf16   bf16x8 __attribute__((ext_vector_type(8)));

#define NS    32768
#define KC    1024
#define INV_T 100.0f
#define TAU   2.0f

// ws layout (float offsets)
#define C2_OFF   0
#define SUMM_OFF 1024                      // [n][32 blocks] float2 = 8 MB
#define SUMM_SZ  (NS * 32 * 2)
#define HIST_OFF (SUMM_OFF + SUMM_SZ)
#define PD_OFF   (HIST_OFF + KC)
#define PS_OFF   (PD_OFF + 8192)

// Fragment-chunk layouts (16B chunks of 8 bf16):
//  xb: 1024 tiles of 32 samples; chunk = ks*128 + sub*32 + row   (8192 u16/tile)
//  ct: 32 tiles of 32 codes;     chunk = ks*128 + sub*32 + row   (8192 u16/tile)
#define XTILE_U16 8192
#define CTILE_U16 8192

__device__ __forceinline__ u16 f2bf(float f) {
    unsigned u = __float_as_uint(f);
    return (u16)((u + 0x7FFFu + ((u >> 16) & 1u)) >> 16);
}

__device__ __forceinline__ void gload_lds16(const void* g, void* l) {
    __builtin_amdgcn_global_load_lds((const __attribute__((address_space(1))) void*)g,
                                     (__attribute__((address_space(3))) void*)l, 16, 0, 0);
}

// --------------------- x fp32 -> bf16 fragment-chunk tiles (1024 blocks) ----
__global__ __launch_bounds__(256) void vq_xcvt(const float* __restrict__ x,
                                               u16* __restrict__ xb) {
    const int tl = blockIdx.x;            // 32-sample tile
    const int t = threadIdx.x;
    const float* src = x + (size_t)tl * 32 * 256;
    u16* dst = xb + (size_t)tl * XTILE_U16;
    #pragma unroll
    for (int j = 0; j < 4; ++j) {
        int row = j * 8 + (t >> 5);       // 0..31
        int kq0 = (t & 31) * 2;           // float4 index, step 2
        #pragma unroll
        for (int h = 0; h < 2; ++h) {
            int kq = kq0 + h;             // 0..63
            float4 v = reinterpret_cast<const float4*>(src)[(size_t)row * 64 + kq];
            int kk = kq * 4;
            int kss = kk >> 5;            // 32-k slice 0..7
            int sub = (kk >> 3) & 3;      // k-octet within slice
            int half = kq & 1;
            ushort4 o;
            o.x = f2bf(v.x); o.y = f2bf(v.y); o.z = f2bf(v.z); o.w = f2bf(v.w);
            *reinterpret_cast<ushort4*>(
                dst + ((size_t)kss * 128 + sub * 32 + row) * 8 + half * 4) = o;
        }
    }
}

// --------------- cb prep: exact c2 + tiled bf16 codebook (64 blocks) ----
__global__ __launch_bounds__(256) void vq_cbprep(const float* __restrict__ cb,
                                                 u16* __restrict__ ct,
                                                 float* __restrict__ c2) {
    const int b = blockIdx.x;        // 64 blocks
    const int t = threadIdx.x, w = t >> 6, lane = t & 63;

    // c2 for 16 codes (exact fp32)
    #pragma unroll
    for (int i = 0; i < 4; ++i) {
        int g = b * 16 + i * 4 + w;
        float4 v = reinterpret_cast<const float4*>(cb)[(size_t)g * 64 + lane];
        float s = v.x * v.x + v.y * v.y + v.z * v.z + v.w * v.w;
        #pragma unroll
        for (int off = 32; off; off >>= 1) s += __shfl_xor(s, off);
        if (lane == 0) c2[g] = s;
    }

    // tiled bf16: tile T = b>>1 (32 codes), part p = b&1 -> chunks [p*512, p*512+512)
    const int T = b >> 1, p = b & 1;
    #pragma unroll
    for (int i = 0; i < 2; ++i) {
        int c = p * 512 + i * 256 + t;            // chunk 0..1023
        int ks = c >> 7, sub = (c >> 5) & 3, row = c & 31;
        const float* srcp = cb + (size_t)(T * 32 + row) * 256 + ks * 32 + sub * 8;
        float4 a0 = *reinterpret_cast<const float4*>(srcp);
        float4 a1 = *reinterpret_cast<const float4*>(srcp + 4);
        bf16x8 v;
        v[0]=(__bf16)a0.x; v[1]=(__bf16)a0.y; v[2]=(__bf16)a0.z; v[3]=(__bf16)a0.w;
        v[4]=(__bf16)a1.x; v[5]=(__bf16)a1.y; v[6]=(__bf16)a1.z; v[7]=(__bf16)a1.w;
        *reinterpret_cast<bf16x8*>(ct + (size_t)T * CTILE_U16 + (size_t)c * 8) = v;
    }
}

// ---- distance MFMA: swapped operands (codes=rows, samples=cols).
//      A (32 samples/wave) persistent in regs; B = 32-code tiles dbuf via LDS
//      (2x16KB). grid 1024 = 256 sample-groups x 4 quarters; 4 blocks/CU.
__global__ __launch_bounds__(256, 4) void vq_dist(const u16* __restrict__ xb,
                                                  const u16* __restrict__ ct,
                                                  const float* __restrict__ c2,
                                                  float2* __restrict__ summ) {
    __shared__ __align__(16) u16 Bs[2][CTILE_U16];   // 2 x 16 KB

    // XCD swizzle: each XCD owns 32 sample-groups x 4 quarters
    const int id = blockIdx.x;
    const int xcd = id & 7, j = id >> 3;         // j 0..127
    const int sq = xcd * 32 + (j >> 2);          // sample group 0..255 (128 samples)
    const int q  = j & 3;                        // code quarter 0..3
    const int sBase = sq * 128;

    const int t = threadIdx.x, w = t >> 6, lane = t & 63;
    const int lo16 = lane & 15, hi = lane >> 4;
    const int hi4 = hi * 4;

    #define STAGE(buf, bt)                                                        \
        do {                                                                      \
            const u16* bT_ = ct + (size_t)(bt) * CTILE_U16;                       \
            _Pragma("unroll")                                                     \
            for (int i_ = 0; i_ < 4; ++i_) {                                      \
                int c0_ = (i_ * 4 + w) * 64;                                      \
                gload_lds16(bT_ + (size_t)(c0_ + lane) * 8, &Bs[buf][c0_ * 8]);   \
            }                                                                     \
        } while (0)

    STAGE(0, q * 8);

    // A-operand: 32 samples x 256 k, persistent (64 regs)
    const u16* aT = xb + (size_t)(sq * 4 + w) * XTILE_U16;
    bf16x8 af[2][8];
    #pragma unroll
    for (int sm = 0; sm < 2; ++sm)
        #pragma unroll
        for (int ks = 0; ks < 8; ++ks)
            af[sm][ks] = *reinterpret_cast<const bf16x8*>(
                aT + ((size_t)ks * 128 + hi * 32 + sm * 16 + lo16) * 8);
    __syncthreads();

    int cur = 0;
    for (int tt = 0; tt < 8; ++tt) {
        if (tt < 7) STAGE(cur ^ 1, q * 8 + tt + 1);

        f32x4 acc[2][2];                 // [code-group cn][sample-group sm]
        #pragma unroll
        for (int cn = 0; cn < 2; ++cn)
            #pragma unroll
            for (int sm = 0; sm < 2; ++sm) acc[cn][sm] = (f32x4)0.f;

        const u16* bsc = &Bs[cur][0];
        #pragma unroll
        for (int ks = 0; ks < 8; ++ks) {
            bf16x8 bfr[2];
            #pragma unroll
            for (int cn = 0; cn < 2; ++cn)
                bfr[cn] = *reinterpret_cast<const bf16x8*>(
                    &bsc[((size_t)ks * 128 + hi * 32 + cn * 16 + lo16) * 8]);
            #pragma unroll
            for (int cn = 0; cn < 2; ++cn)
                #pragma unroll
                for (int sm = 0; sm < 2; ++sm)
                    acc[cn][sm] = __builtin_amdgcn_mfma_f32_16x16x32_bf16(
                        bfr[cn], af[sm][ks], acc[cn][sm], 0, 0, 0);
        }

        // Epilogue: lane owns sample (sm*16+lo16) x codes (cn*16 + hi4 + r).
        const int cBase = q * 256 + tt * 32;
        float c2v[2][4];
        #pragma unroll
        for (int cn = 0; cn < 2; ++cn)
            #pragma unroll
            for (int r = 0; r < 4; ++r)
                c2v[cn][r] = c2[cBase + cn * 16 + hi4 + r];

        #pragma unroll
        for (int sm = 0; sm < 2; ++sm) {
            float dd[2][4];
            #pragma unroll
            for (int cn = 0; cn < 2; ++cn)
                #pragma unroll
                for (int r = 0; r < 4; ++r)
                    dd[cn][r] = fmaf(-2.0f, acc[cn][sm][r], c2v[cn][r]);
            // in-register min over 8 codes
            float bm = dd[0][0];
            #pragma unroll
            for (int cn = 0; cn < 2; ++cn)
                #pragma unroll
                for (int r = 0; r < 4; ++r) bm = fminf(bm, dd[cn][r]);
            // cross-hi min (2 shfls; lanes share lo16)
            bm = fminf(bm, __shfl_xor(bm, 16));
            bm = fminf(bm, __shfl_xor(bm, 32));
            const float thr = bm + TAU;
            // local 32-bit mask: bit cn*16 + hi4 + r
            u32 m32 = 0;
            #pragma unroll
            for (int cn = 0; cn < 2; ++cn)
                #pragma unroll
                for (int r = 0; r < 4; ++r)
                    m32 |= (dd[cn][r] < thr ? 1u : 0u) << (cn * 16 + hi4 + r);
            m32 |= __shfl_xor(m32, 16);
            m32 |= __shfl_xor(m32, 32);
            if (hi == 0) {
                const int R = sBase + w * 32 + sm * 16 + lo16;
                float2 o; o.x = bm; o.y = __uint_as_float(m32);
                summ[(size_t)R * 32 + q * 8 + tt] = o;
            }
        }
        __syncthreads();
        cur ^= 1;
    }
    #undef STAGE
}

// ---------- exact fp32 refine: ballot-driven active blocks, 4-way ILP ----
__global__ __launch_bounds__(256) void vq_refine(const float* __restrict__ x,
                                                 const float* __restrict__ cb,
                                                 const float* __restrict__ c2,
                                                 const float2* __restrict__ summ,
                                                 float* __restrict__ hist,
                                                 float* __restrict__ pd,
                                                 float* __restrict__ ps,
                                                 float* __restrict__ outq,
                                                 float* __restrict__ out_idx_f) {
    __shared__ int   cd_k[4][128];
    __shared__ float cd_d[4][128];
    __shared__ float rd[4], rs[4];

    const int wid = threadIdx.x >> 6, lane = threadIdx.x & 63;
    const int s = blockIdx.x * 4 + wid;
    const float4 xv = reinterpret_cast<const float4*>(x)[(size_t)s * 64 + lane];

    float x2s = xv.x * xv.x + xv.y * xv.y + xv.z * xv.z + xv.w * xv.w;
    #pragma unroll
    for (int off = 32; off; off >>= 1) x2s += __shfl_xor(x2s, off);

    // parallel load of all 32 block summaries (lane hb holds block hb; dup in hi half)
    const float2 smv = summ[(size_t)s * 32 + (lane & 31)];
    float gm = smv.x;
    #pragma unroll
    for (int off = 1; off < 32; off <<= 1) gm = fminf(gm, __shfl_xor(gm, off));
    const float lim = gm + TAU;

    // wave-uniform active-block mask (typically 1-2 bits)
    u64 act = __ballot((lane < 32) && (smv.x <= lim));

    const float4* cb4 = reinterpret_cast<const float4*>(cb);
    float m = 3.4e38f, S1 = 0.f, S2 = 0.f;
    int bk = 0, cnt = 0;

    while (act) {
        const int hb = __ffsll(act) - 1; act &= act - 1;
        u32 mk = __float_as_uint(__shfl(smv.y, hb));
        while (mk) {
            int vc = 1;
            int b0 = __ffs(mk) - 1; mk &= mk - 1;
            int k0 = hb * 32 + b0, k1 = k0, k2 = k0, k3 = k0;
            if (mk) { int b = __ffs(mk) - 1; mk &= mk - 1; k1 = hb * 32 + b; vc = 2; }
            if (mk) { int b = __ffs(mk) - 1; mk &= mk - 1; k2 = hb * 32 + b; vc = 3; }
            if (mk) { int b = __ffs(mk) - 1; mk &= mk - 1; k3 = hb * 32 + b; vc = 4; }

            float4 cv0 = cb4[(size_t)k0 * 64 + lane];
            float4 cv1 = cb4[(size_t)k1 * 64 + lane];
            float4 cv2 = cb4[(size_t)k2 * 64 + lane];
            float4 cv3 = cb4[(size_t)k3 * 64 + lane];
            float r0 = xv.x*cv0.x + xv.y*cv0.y + xv.z*cv0.z + xv.w*cv0.w;
            float r1 = xv.x*cv1.x + xv.y*cv1.y + xv.z*cv1.z + xv.w*cv1.w;
            float r2 = xv.x*cv2.x + xv.y*cv2.y + xv.z*cv2.z + xv.w*cv2.w;
            float r3 = xv.x*cv3.x + xv.y*cv3.y + xv.z*cv3.z + xv.w*cv3.w;
            #pragma unroll
            for (int off = 32; off; off >>= 1) {
                r0 += __shfl_xor(r0, off);
                r1 += __shfl_xor(r1, off);
                r2 += __shfl_xor(r2, off);
                r3 += __shfl_xor(r3, off);
            }
            float dk[4];
            dk[0] = (x2s - 2.0f * r0) + c2[k0];
            dk[1] = (x2s - 2.0f * r1) + c2[k1];
            dk[2] = (x2s - 2.0f * r2) + c2[k2];
            dk[3] = (x2s - 2.0f * r3) + c2[k3];
            int kk[4] = {k0, k1, k2, k3};

            #pragma unroll
            for (int jj = 0; jj < 4; ++jj) {
                if (jj >= vc) break;
                float d = dk[jj];
                if (lane == 0 && cnt < 128) { cd_k[wid][cnt] = kk[jj]; cd_d[wid][cnt] = d; }
                ++cnt;
                if (S1 == 0.f)   { m = d; S1 = 1.f; S2 = 0.f; bk = kk[jj]; }
                else if (d < m)  { float f = __expf((d - m) * INV_T);
                                   S2 = f * (S2 + (m - d) * S1);
                                   S1 = S1 * f + 1.f; m = d; bk = kk[jj]; }
                else             { float e = __expf((m - d) * INV_T);
                                   S1 += e; S2 += e * (d - m); }
            }
        }
    }
    float sent = S2 * INV_T / S1 + logf(S1);
    if (lane == 0) { rd[wid] = m; rs[wid] = sent; }
    __syncthreads();

    if (cnt > 128) cnt = 128;
    for (int c = lane; c < cnt; c += 64) {
        float dkv = cd_d[wid][c]; int k = cd_k[wid][c];
        atomicAdd(&hist[k], __expf((m - dkv) * INV_T) / S1);
    }

    reinterpret_cast<float4*>(outq)[(size_t)s * 64 + lane] = cb4[(size_t)bk * 64 + lane];
    if (lane == 0) out_idx_f[s] = (float)bk;

    if (threadIdx.x == 0) {
        pd[blockIdx.x] = rd[0] + rd[1] + rd[2] + rd[3];
        ps[blockIdx.x] = rs[0] + rs[1] + rs[2] + rs[3];
    }
}

// -------------------------------------------------------------- finalize ----
__global__ __launch_bounds__(256) void vq_finalize(const float* __restrict__ hist,
                                                   const float* __restrict__ pd,
                                                   const float* __restrict__ ps,
                                                   float* __restrict__ loss_out) {
    float ae = 0.f, sd = 0.f, se = 0.f;
    for (int k = threadIdx.x; k < KC; k += 256) {
        float p = hist[k] * (1.0f / (float)NS);
        ae += -p * logf(p + 1e-5f);
    }
    for (int b = threadIdx.x; b < 8192; b += 256) { sd += pd[b]; se += ps[b]; }
    #pragma unroll
    for (int off = 32; off; off >>= 1) {
        ae += __shfl_xor(ae, off); sd += __shfl_xor(sd, off); se += __shfl_xor(se, off);
    }
    __shared__ float r[3][4];
    int wid = threadIdx.x >> 6, lane = threadIdx.x & 63;
    if (lane == 0) { r[0][wid] = ae; r[1][wid] = sd; r[2][wid] = se; }
    __syncthreads();
    if (threadIdx.x == 0) {
        float AE = r[0][0] + r[0][1] + r[0][2] + r[0][3];
        float SD = r[1][0] + r[1][1] + r[1][2] + r[1][3];
        float SE = r[2][0] + r[2][1] + r[2][2] + r[2][3];
        float latent = 1.25f * SD / 8388608.0f;
        loss_out[0] = latent + 0.1f * (SE * (1.0f / (float)NS) - AE);
    }
}

extern "C" void kernel_launch(void* const* d_in, const int* in_sizes, int n_in,
                              void* d_out, int out_size, void* d_ws, size_t ws_size,
                              hipStream_t stream) {
    const float* x  = (const float*)d_in[0];
    const float* cb = (const float*)d_in[1];
    float* out = (float*)d_out;
    float* ws  = (float*)d_ws;

    // bf16 scratch in d_out's quantized region (overwritten by refine later):
    u16* xb = (u16*)d_out;                       // 16 MB
    u16* ct = (u16*)(out + 4194304);             // 512 KB

    hipMemsetAsync(ws + HIST_OFF, 0, KC * sizeof(float), stream);

    vq_xcvt<<<1024, 256, 0, stream>>>(x, xb);
    vq_cbprep<<<64, 256, 0, stream>>>(cb, ct, ws + C2_OFF);
    vq_dist<<<1024, 256, 0, stream>>>(xb, ct, ws + C2_OFF, (float2*)(ws + SUMM_OFF));
    vq_refine<<<NS / 4, 256, 0, stream>>>(x, cb, ws + C2_OFF,
                                          (const float2*)(ws + SUMM_OFF),
                                          ws + HIST_OFF, ws + PD_OFF, ws + PS_OFF,
                                          out, out + 8388609);
    vq_finalize<<<1, 256, 0, stream>>>(ws + HIST_OFF, ws + PD_OFF, ws + PS_OFF,
                                       out + 8388608);
}

// Round 14
// 88.576 us; speedup vs baseline: 1.2909x; 1.0458x over previous
//
#include <hip/hip_runtime.h>
#include <math.h>

typedef unsigned short u16;
typedef unsigned int u32;
typedef unsigned long long u64;
typedef float    f32x4  __attribute__((ext_vector_type(4)));
typedef __bf16   bf16x8 __attribute__((ext_vector_type(8)));

#define NS    32768
#define KC    1024
#define INV_T 100.0f
#define TAU   2.0f

// ws layout (float offsets)
#define C2_OFF   0
#define SUMM_OFF 1024                      // [n][32 blocks] float2 = 8 MB
#define SUMM_SZ  (NS * 32 * 2)
#define HIST_OFF (SUMM_OFF + SUMM_SZ)
#define PD_OFF   (HIST_OFF + KC)
#define PS_OFF   (PD_OFF + 8192)

// Fragment-chunk layouts (16B chunks of 8 bf16):
//  xb: 1024 tiles of 32 samples; chunk = ks*128 + sub*32 + row   (8192 u16/tile)
//  ct: 32 tiles of 32 codes;     chunk = ks*128 + sub*32 + row   (8192 u16/tile)
#define XTILE_U16 8192
#define CTILE_U16 8192

__device__ __forceinline__ u16 f2bf(float f) {
    unsigned u = __float_as_uint(f);
    return (u16)((u + 0x7FFFu + ((u >> 16) & 1u)) >> 16);
}

__device__ __forceinline__ void gload_lds16(const void* g, void* l) {
    __builtin_amdgcn_global_load_lds((const __attribute__((address_space(1))) void*)g,
                                     (__attribute__((address_space(3))) void*)l, 16, 0, 0);
}

// --------------------- x fp32 -> bf16 fragment-chunk tiles (1024 blocks) ----
__global__ __launch_bounds__(256) void vq_xcvt(const float* __restrict__ x,
                                               u16* __restrict__ xb) {
    const int tl = blockIdx.x;            // 32-sample tile
    const int t = threadIdx.x;
    const float* src = x + (size_t)tl * 32 * 256;
    u16* dst = xb + (size_t)tl * XTILE_U16;
    #pragma unroll
    for (int j = 0; j < 4; ++j) {
        int row = j * 8 + (t >> 5);       // 0..31
        int kq0 = (t & 31) * 2;           // float4 index, step 2
        #pragma unroll
        for (int h = 0; h < 2; ++h) {
            int kq = kq0 + h;             // 0..63
            float4 v = reinterpret_cast<const float4*>(src)[(size_t)row * 64 + kq];
            int kk = kq * 4;
            int kss = kk >> 5;            // 32-k slice 0..7
            int sub = (kk >> 3) & 3;      // k-octet within slice
            int half = kq & 1;
            ushort4 o;
            o.x = f2bf(v.x); o.y = f2bf(v.y); o.z = f2bf(v.z); o.w = f2bf(v.w);
            *reinterpret_cast<ushort4*>(
                dst + ((size_t)kss * 128 + sub * 32 + row) * 8 + half * 4) = o;
        }
    }
}

// ---- cb prep: exact c2 + tiled bf16 codebook + hist zeroing (64 blocks) ----
__global__ __launch_bounds__(256) void vq_cbprep(const float* __restrict__ cb,
                                                 u16* __restrict__ ct,
                                                 float* __restrict__ c2,
                                                 float* __restrict__ hist) {
    const int b = blockIdx.x;        // 64 blocks
    const int t = threadIdx.x, w = t >> 6, lane = t & 63;

    // zero this block's 16 hist bins (replaces the hipMemsetAsync graph node)
    if (t < 16) hist[b * 16 + t] = 0.f;

    // c2 for 16 codes (exact fp32)
    #pragma unroll
    for (int i = 0; i < 4; ++i) {
        int g = b * 16 + i * 4 + w;
        float4 v = reinterpret_cast<const float4*>(cb)[(size_t)g * 64 + lane];
        float s = v.x * v.x + v.y * v.y + v.z * v.z + v.w * v.w;
        #pragma unroll
        for (int off = 32; off; off >>= 1) s += __shfl_xor(s, off);
        if (lane == 0) c2[g] = s;
    }

    // tiled bf16: tile T = b>>1 (32 codes), part p = b&1 -> chunks [p*512, p*512+512)
    const int T = b >> 1, p = b & 1;
    #pragma unroll
    for (int i = 0; i < 2; ++i) {
        int c = p * 512 + i * 256 + t;            // chunk 0..1023
        int ks = c >> 7, sub = (c >> 5) & 3, row = c & 31;
        const float* srcp = cb + (size_t)(T * 32 + row) * 256 + ks * 32 + sub * 8;
        float4 a0 = *reinterpret_cast<const float4*>(srcp);
        float4 a1 = *reinterpret_cast<const float4*>(srcp + 4);
        bf16x8 v;
        v[0]=(__bf16)a0.x; v[1]=(__bf16)a0.y; v[2]=(__bf16)a0.z; v[3]=(__bf16)a0.w;
        v[4]=(__bf16)a1.x; v[5]=(__bf16)a1.y; v[6]=(__bf16)a1.z; v[7]=(__bf16)a1.w;
        *reinterpret_cast<bf16x8*>(ct + (size_t)T * CTILE_U16 + (size_t)c * 8) = v;
    }
}

// ---- distance MFMA: swapped operands (codes=rows, samples=cols).
//      A (32 samples/wave) persistent in regs; B = 32-code tiles dbuf via LDS
//      (2x16KB). grid 1024 = 256 sample-groups x 4 quarters; 4 blocks/CU.
__global__ __launch_bounds__(256, 4) void vq_dist(const u16* __restrict__ xb,
                                                  const u16* __restrict__ ct,
                                                  const float* __restrict__ c2,
                                                  float2* __restrict__ summ) {
    __shared__ __align__(16) u16 Bs[2][CTILE_U16];   // 2 x 16 KB

    // XCD swizzle: each XCD owns 32 sample-groups x 4 quarters
    const int id = blockIdx.x;
    const int xcd = id & 7, j = id >> 3;         // j 0..127
    const int sq = xcd * 32 + (j >> 2);          // sample group 0..255 (128 samples)
    const int q  = j & 3;                        // code quarter 0..3
    const int sBase = sq * 128;

    const int t = threadIdx.x, w = t >> 6, lane = t & 63;
    const int lo16 = lane & 15, hi = lane >> 4;
    const int hi4 = hi * 4;

    #define STAGE(buf, bt)                                                        \
        do {                                                                      \
            const u16* bT_ = ct + (size_t)(bt) * CTILE_U16;                       \
            _Pragma("unroll")                                                     \
            for (int i_ = 0; i_ < 4; ++i_) {                                      \
                int c0_ = (i_ * 4 + w) * 64;                                      \
                gload_lds16(bT_ + (size_t)(c0_ + lane) * 8, &Bs[buf][c0_ * 8]);   \
            }                                                                     \
        } while (0)

    STAGE(0, q * 8);

    // A-operand: 32 samples x 256 k, persistent (64 regs)
    const u16* aT = xb + (size_t)(sq * 4 + w) * XTILE_U16;
    bf16x8 af[2][8];
    #pragma unroll
    for (int sm = 0; sm < 2; ++sm)
        #pragma unroll
        for (int ks = 0; ks < 8; ++ks)
            af[sm][ks] = *reinterpret_cast<const bf16x8*>(
                aT + ((size_t)ks * 128 + hi * 32 + sm * 16 + lo16) * 8);
    __syncthreads();

    int cur = 0;
    for (int tt = 0; tt < 8; ++tt) {
        if (tt < 7) STAGE(cur ^ 1, q * 8 + tt + 1);

        f32x4 acc[2][2];                 // [code-group cn][sample-group sm]
        #pragma unroll
        for (int cn = 0; cn < 2; ++cn)
            #pragma unroll
            for (int sm = 0; sm < 2; ++sm) acc[cn][sm] = (f32x4)0.f;

        const u16* bsc = &Bs[cur][0];
        #pragma unroll
        for (int ks = 0; ks < 8; ++ks) {
            bf16x8 bfr[2];
            #pragma unroll
            for (int cn = 0; cn < 2; ++cn)
                bfr[cn] = *reinterpret_cast<const bf16x8*>(
                    &bsc[((size_t)ks * 128 + hi * 32 + cn * 16 + lo16) * 8]);
            #pragma unroll
            for (int cn = 0; cn < 2; ++cn)
                #pragma unroll
                for (int sm = 0; sm < 2; ++sm)
                    acc[cn][sm] = __builtin_amdgcn_mfma_f32_16x16x32_bf16(
                        bfr[cn], af[sm][ks], acc[cn][sm], 0, 0, 0);
        }

        // Epilogue: lane owns sample (sm*16+lo16) x codes (cn*16 + hi4 + r).
        const int cBase = q * 256 + tt * 32;
        float c2v[2][4];
        #pragma unroll
        for (int cn = 0; cn < 2; ++cn)
            #pragma unroll
            for (int r = 0; r < 4; ++r)
                c2v[cn][r] = c2[cBase + cn * 16 + hi4 + r];

        #pragma unroll
        for (int sm = 0; sm < 2; ++sm) {
            float dd[2][4];
            #pragma unroll
            for (int cn = 0; cn < 2; ++cn)
                #pragma unroll
                for (int r = 0; r < 4; ++r)
                    dd[cn][r] = fmaf(-2.0f, acc[cn][sm][r], c2v[cn][r]);
            // in-register min over 8 codes
            float bm = dd[0][0];
            #pragma unroll
            for (int cn = 0; cn < 2; ++cn)
                #pragma unroll
                for (int r = 0; r < 4; ++r) bm = fminf(bm, dd[cn][r]);
            // cross-hi min (2 shfls; lanes share lo16)
            bm = fminf(bm, __shfl_xor(bm, 16));
            bm = fminf(bm, __shfl_xor(bm, 32));
            const float thr = bm + TAU;
            // local 32-bit mask: bit cn*16 + hi4 + r
            u32 m32 = 0;
            #pragma unroll
            for (int cn = 0; cn < 2; ++cn)
                #pragma unroll
                for (int r = 0; r < 4; ++r)
                    m32 |= (dd[cn][r] < thr ? 1u : 0u) << (cn * 16 + hi4 + r);
            m32 |= __shfl_xor(m32, 16);
            m32 |= __shfl_xor(m32, 32);
            if (hi == 0) {
                const int R = sBase + w * 32 + sm * 16 + lo16;
                float2 o; o.x = bm; o.y = __uint_as_float(m32);
                summ[(size_t)R * 32 + q * 8 + tt] = o;
            }
        }
        __syncthreads();
        cur ^= 1;
    }
    #undef STAGE
}

// ---------- exact fp32 refine: ballot-driven active blocks, 4-way ILP ----
__global__ __launch_bounds__(256) void vq_refine(const float* __restrict__ x,
                                                 const float* __restrict__ cb,
                                                 const float* __restrict__ c2,
                                                 const float2* __restrict__ summ,
                                                 float* __restrict__ hist,
                                                 float* __restrict__ pd,
                                                 float* __restrict__ ps,
                                                 float* __restrict__ outq,
                                                 float* __restrict__ out_idx_f) {
    __shared__ int   cd_k[4][128];
    __shared__ float cd_d[4][128];
    __shared__ float rd[4], rs[4];

    const int wid = threadIdx.x >> 6, lane = threadIdx.x & 63;
    const int s = blockIdx.x * 4 + wid;
    const float4 xv = reinterpret_cast<const float4*>(x)[(size_t)s * 64 + lane];

    float x2s = xv.x * xv.x + xv.y * xv.y + xv.z * xv.z + xv.w * xv.w;
    #pragma unroll
    for (int off = 32; off; off >>= 1) x2s += __shfl_xor(x2s, off);

    // parallel load of all 32 block summaries (lane hb holds block hb; dup in hi half)
    const float2 smv = summ[(size_t)s * 32 + (lane & 31)];
    float gm = smv.x;
    #pragma unroll
    for (int off = 1; off < 32; off <<= 1) gm = fminf(gm, __shfl_xor(gm, off));
    const float lim = gm + TAU;

    // wave-uniform active-block mask (typically 1-2 bits)
    u64 act = __ballot((lane < 32) && (smv.x <= lim));

    const float4* cb4 = reinterpret_cast<const float4*>(cb);
    float m = 3.4e38f, S1 = 0.f, S2 = 0.f;
    int bk = 0, cnt = 0;

    while (act) {
        const int hb = __ffsll(act) - 1; act &= act - 1;
        u32 mk = __float_as_uint(__shfl(smv.y, hb));
        while (mk) {
            int vc = 1;
            int b0 = __ffs(mk) - 1; mk &= mk - 1;
            int k0 = hb * 32 + b0, k1 = k0, k2 = k0, k3 = k0;
            if (mk) { int b = __ffs(mk) - 1; mk &= mk - 1; k1 = hb * 32 + b; vc = 2; }
            if (mk) { int b = __ffs(mk) - 1; mk &= mk - 1; k2 = hb * 32 + b; vc = 3; }
            if (mk) { int b = __ffs(mk) - 1; mk &= mk - 1; k3 = hb * 32 + b; vc = 4; }

            float4 cv0 = cb4[(size_t)k0 * 64 + lane];
            float4 cv1 = cb4[(size_t)k1 * 64 + lane];
            float4 cv2 = cb4[(size_t)k2 * 64 + lane];
            float4 cv3 = cb4[(size_t)k3 * 64 + lane];
            float r0 = xv.x*cv0.x + xv.y*cv0.y + xv.z*cv0.z + xv.w*cv0.w;
            float r1 = xv.x*cv1.x + xv.y*cv1.y + xv.z*cv1.z + xv.w*cv1.w;
            float r2 = xv.x*cv2.x + xv.y*cv2.y + xv.z*cv2.z + xv.w*cv2.w;
            float r3 = xv.x*cv3.x + xv.y*cv3.y + xv.z*cv3.z + xv.w*cv3.w;
            #pragma unroll
            for (int off = 32; off; off >>= 1) {
                r0 += __shfl_xor(r0, off);
                r1 += __shfl_xor(r1, off);
                r2 += __shfl_xor(r2, off);
                r3 += __shfl_xor(r3, off);
            }
            float dk[4];
            dk[0] = (x2s - 2.0f * r0) + c2[k0];
            dk[1] = (x2s - 2.0f * r1) + c2[k1];
            dk[2] = (x2s - 2.0f * r2) + c2[k2];
            dk[3] = (x2s - 2.0f * r3) + c2[k3];
            int kk[4] = {k0, k1, k2, k3};

            #pragma unroll
            for (int jj = 0; jj < 4; ++jj) {
                if (jj >= vc) break;
                float d = dk[jj];
                if (lane == 0 && cnt < 128) { cd_k[wid][cnt] = kk[jj]; cd_d[wid][cnt] = d; }
                ++cnt;
                if (S1 == 0.f)   { m = d; S1 = 1.f; S2 = 0.f; bk = kk[jj]; }
                else if (d < m)  { float f = __expf((d - m) * INV_T);
                                   S2 = f * (S2 + (m - d) * S1);
                                   S1 = S1 * f + 1.f; m = d; bk = kk[jj]; }
                else             { float e = __expf((m - d) * INV_T);
                                   S1 += e; S2 += e * (d - m); }
            }
        }
    }
    float sent = S2 * INV_T / S1 + logf(S1);
    if (lane == 0) { rd[wid] = m; rs[wid] = sent; }
    __syncthreads();

    if (cnt > 128) cnt = 128;
    for (int c = lane; c < cnt; c += 64) {
        float dkv = cd_d[wid][c]; int k = cd_k[wid][c];
        atomicAdd(&hist[k], __expf((m - dkv) * INV_T) / S1);
    }

    reinterpret_cast<float4*>(outq)[(size_t)s * 64 + lane] = cb4[(size_t)bk * 64 + lane];
    if (lane == 0) out_idx_f[s] = (float)bk;

    if (threadIdx.x == 0) {
        pd[blockIdx.x] = rd[0] + rd[1] + rd[2] + rd[3];
        ps[blockIdx.x] = rs[0] + rs[1] + rs[2] + rs[3];
    }
}

// -------------------------------------------------------------- finalize ----
__global__ __launch_bounds__(256) void vq_finalize(const float* __restrict__ hist,
                                                   const float* __restrict__ pd,
                                                   const float* __restrict__ ps,
                                                   float* __restrict__ loss_out) {
    float ae = 0.f, sd = 0.f, se = 0.f;
    for (int k = threadIdx.x; k < KC; k += 256) {
        float p = hist[k] * (1.0f / (float)NS);
        ae += -p * logf(p + 1e-5f);
    }
    for (int b = threadIdx.x; b < 8192; b += 256) { sd += pd[b]; se += ps[b]; }
    #pragma unroll
    for (int off = 32; off; off >>= 1) {
        ae += __shfl_xor(ae, off); sd += __shfl_xor(sd, off); se += __shfl_xor(se, off);
    }
    __shared__ float r[3][4];
    int wid = threadIdx.x >> 6, lane = threadIdx.x & 63;
    if (lane == 0) { r[0][wid] = ae; r[1][wid] = sd; r[2][wid] = se; }
    __syncthreads();
    if (threadIdx.x == 0) {
        float AE = r[0][0] + r[0][1] + r[0][2] + r[0][3];
        float SD = r[1][0] + r[1][1] + r[1][2] + r[1][3];
        float SE = r[2][0] + r[2][1] + r[2][2] + r[2][3];
        float latent = 1.25f * SD / 8388608.0f;
        loss_out[0] = latent + 0.1f * (SE * (1.0f / (float)NS) - AE);
    }
}

extern "C" void kernel_launch(void* const* d_in, const int* in_sizes, int n_in,
                              void* d_out, int out_size, void* d_ws, size_t ws_size,
                              hipStream_t stream) {
    const float* x  = (const float*)d_in[0];
    const float* cb = (const float*)d_in[1];
    float* out = (float*)d_out;
    float* ws  = (float*)d_ws;

    // bf16 scratch in d_out's quantized region (overwritten by refine later):
    u16* xb = (u16*)d_out;                       // 16 MB
    u16* ct = (u16*)(out + 4194304);             // 512 KB

    vq_xcvt<<<1024, 256, 0, stream>>>(x, xb);
    vq_cbprep<<<64, 256, 0, stream>>>(cb, ct, ws + C2_OFF, ws + HIST_OFF);
    vq_dist<<<1024, 256, 0, stream>>>(xb, ct, ws + C2_OFF, (float2*)(ws + SUMM_OFF));
    vq_refine<<<NS / 4, 256, 0, stream>>>(x, cb, ws + C2_OFF,
                                          (const float2*)(ws + SUMM_OFF),
                                          ws + HIST_OFF, ws + PD_OFF, ws + PS_OFF,
                                          out, out + 8388609);
    vq_finalize<<<1, 256, 0, stream>>>(ws + HIST_OFF, ws + PD_OFF, ws + PS_OFF,
                                       out + 8388608);
}

// Round 15
// 80.863 us; speedup vs baseline: 1.4141x; 1.0954x over previous
//
#include <hip/hip_runtime.h>
#include <math.h>

typedef unsigned short u16;
typedef unsigned int u32;
typedef unsigned long long u64;
typedef float    f32x4  __attribute__((ext_vector_type(4)));
typedef __bf16   bf16x8 __attribute__((ext_vector_type(8)));

#define NS    32768
#define KC    1024
#define INV_T 100.0f
#define TAU   1.25f

// ws layout (float offsets)
#define C2_OFF   0                          // 1024
#define X2_OFF   1024                       // 32768
#define SUMM_OFF (1024 + 32768)             // [n][32 blocks] float2 = 8 MB
#define SUMM_SZ  (NS * 32 * 2)
#define HIST_OFF (SUMM_OFF + SUMM_SZ)       // 1024
#define PD_OFF   (HIST_OFF + KC)            // 4096
#define PS_OFF   (PD_OFF + 4096)            // 4096

// Fragment-chunk layouts (16B chunks of 8 bf16):
//  xb: 1024 tiles of 32 samples; chunk = ks*128 + sub*32 + row   (8192 u16/tile)
//  ct: 32 tiles of 32 codes;     chunk = ks*128 + sub*32 + row   (8192 u16/tile)
#define XTILE_U16 8192
#define CTILE_U16 8192

__device__ __forceinline__ u16 f2bf(float f) {
    unsigned u = __float_as_uint(f);
    return (u16)((u + 0x7FFFu + ((u >> 16) & 1u)) >> 16);
}

__device__ __forceinline__ void gload_lds16(const void* g, void* l) {
    __builtin_amdgcn_global_load_lds((const __attribute__((address_space(1))) void*)g,
                                     (__attribute__((address_space(3))) void*)l, 16, 0, 0);
}

// ---------- x fp32 -> bf16 fragment-chunk tiles + exact x^2 (1024 blocks) ----
__global__ __launch_bounds__(256) void vq_xcvt(const float* __restrict__ x,
                                               u16* __restrict__ xb,
                                               float* __restrict__ x2) {
    const int tl = blockIdx.x;            // 32-sample tile
    const int t = threadIdx.x;
    const float* src = x + (size_t)tl * 32 * 256;
    u16* dst = xb + (size_t)tl * XTILE_U16;
    #pragma unroll
    for (int j = 0; j < 4; ++j) {
        int row = j * 8 + (t >> 5);       // 0..31
        int kq0 = (t & 31) * 2;           // float4 index, step 2
        float sq = 0.f;
        #pragma unroll
        for (int h = 0; h < 2; ++h) {
            int kq = kq0 + h;             // 0..63
            float4 v = reinterpret_cast<const float4*>(src)[(size_t)row * 64 + kq];
            sq += v.x * v.x + v.y * v.y + v.z * v.z + v.w * v.w;
            int kk = kq * 4;
            int kss = kk >> 5;            // 32-k slice 0..7
            int sub = (kk >> 3) & 3;      // k-octet within slice
            int half = kq & 1;
            ushort4 o;
            o.x = f2bf(v.x); o.y = f2bf(v.y); o.z = f2bf(v.z); o.w = f2bf(v.w);
            *reinterpret_cast<ushort4*>(
                dst + ((size_t)kss * 128 + sub * 32 + row) * 8 + half * 4) = o;
        }
        // exact fp32 row-norm: reduce over the 32 threads sharing this row
        sq += __shfl_xor(sq, 1);  sq += __shfl_xor(sq, 2);
        sq += __shfl_xor(sq, 4);  sq += __shfl_xor(sq, 8);
        sq += __shfl_xor(sq, 16);
        if ((t & 31) == 0) x2[tl * 32 + row] = sq;
    }
}

// ---- cb prep: exact c2 + tiled bf16 codebook + hist zeroing (64 blocks) ----
__global__ __launch_bounds__(256) void vq_cbprep(const float* __restrict__ cb,
                                                 u16* __restrict__ ct,
                                                 float* __restrict__ c2,
                                                 float* __restrict__ hist) {
    const int b = blockIdx.x;        // 64 blocks
    const int t = threadIdx.x, w = t >> 6, lane = t & 63;

    if (t < 16) hist[b * 16 + t] = 0.f;

    // c2 for 16 codes (exact fp32)
    #pragma unroll
    for (int i = 0; i < 4; ++i) {
        int g = b * 16 + i * 4 + w;
        float4 v = reinterpret_cast<const float4*>(cb)[(size_t)g * 64 + lane];
        float s = v.x * v.x + v.y * v.y + v.z * v.z + v.w * v.w;
        #pragma unroll
        for (int off = 32; off; off >>= 1) s += __shfl_xor(s, off);
        if (lane == 0) c2[g] = s;
    }

    // tiled bf16: tile T = b>>1 (32 codes), part p = b&1 -> chunks [p*512, p*512+512)
    const int T = b >> 1, p = b & 1;
    #pragma unroll
    for (int i = 0; i < 2; ++i) {
        int c = p * 512 + i * 256 + t;            // chunk 0..1023
        int ks = c >> 7, sub = (c >> 5) & 3, row = c & 31;
        const float* srcp = cb + (size_t)(T * 32 + row) * 256 + ks * 32 + sub * 8;
        float4 a0 = *reinterpret_cast<const float4*>(srcp);
        float4 a1 = *reinterpret_cast<const float4*>(srcp + 4);
        bf16x8 v;
        v[0]=(__bf16)a0.x; v[1]=(__bf16)a0.y; v[2]=(__bf16)a0.z; v[3]=(__bf16)a0.w;
        v[4]=(__bf16)a1.x; v[5]=(__bf16)a1.y; v[6]=(__bf16)a1.z; v[7]=(__bf16)a1.w;
        *reinterpret_cast<bf16x8*>(ct + (size_t)T * CTILE_U16 + (size_t)c * 8) = v;
    }
}

// ---- distance MFMA: swapped operands (codes=rows, samples=cols).
//      A (32 samples/wave) persistent in regs; B = 32-code tiles dbuf via LDS
//      (2x16KB). grid 1024 = 256 sample-groups x 4 quarters; 4 blocks/CU.
__global__ __launch_bounds__(256, 4) void vq_dist(const u16* __restrict__ xb,
                                                  const u16* __restrict__ ct,
                                                  const float* __restrict__ c2,
                                                  float2* __restrict__ summ) {
    __shared__ __align__(16) u16 Bs[2][CTILE_U16];   // 2 x 16 KB

    // XCD swizzle: each XCD owns 32 sample-groups x 4 quarters
    const int id = blockIdx.x;
    const int xcd = id & 7, j = id >> 3;         // j 0..127
    const int sq = xcd * 32 + (j >> 2);          // sample group 0..255 (128 samples)
    const int q  = j & 3;                        // code quarter 0..3
    const int sBase = sq * 128;

    const int t = threadIdx.x, w = t >> 6, lane = t & 63;
    const int lo16 = lane & 15, hi = lane >> 4;
    const int hi4 = hi * 4;

    #define STAGE(buf, bt)                                                        \
        do {                                                                      \
            const u16* bT_ = ct + (size_t)(bt) * CTILE_U16;                       \
            _Pragma("unroll")                                                     \
            for (int i_ = 0; i_ < 4; ++i_) {                                      \
                int c0_ = (i_ * 4 + w) * 64;                                      \
                gload_lds16(bT_ + (size_t)(c0_ + lane) * 8, &Bs[buf][c0_ * 8]);   \
            }                                                                     \
        } while (0)

    STAGE(0, q * 8);

    // A-operand: 32 samples x 256 k, persistent (64 regs)
    const u16* aT = xb + (size_t)(sq * 4 + w) * XTILE_U16;
    bf16x8 af[2][8];
    #pragma unroll
    for (int sm = 0; sm < 2; ++sm)
        #pragma unroll
        for (int ks = 0; ks < 8; ++ks)
            af[sm][ks] = *reinterpret_cast<const bf16x8*>(
                aT + ((size_t)ks * 128 + hi * 32 + sm * 16 + lo16) * 8);
    __syncthreads();

    int cur = 0;
    for (int tt = 0; tt < 8; ++tt) {
        if (tt < 7) STAGE(cur ^ 1, q * 8 + tt + 1);

        f32x4 acc[2][2];                 // [code-group cn][sample-group sm]
        #pragma unroll
        for (int cn = 0; cn < 2; ++cn)
            #pragma unroll
            for (int sm = 0; sm < 2; ++sm) acc[cn][sm] = (f32x4)0.f;

        const u16* bsc = &Bs[cur][0];
        #pragma unroll
        for (int ks = 0; ks < 8; ++ks) {
            bf16x8 bfr[2];
            #pragma unroll
            for (int cn = 0; cn < 2; ++cn)
                bfr[cn] = *reinterpret_cast<const bf16x8*>(
                    &bsc[((size_t)ks * 128 + hi * 32 + cn * 16 + lo16) * 8]);
            #pragma unroll
            for (int cn = 0; cn < 2; ++cn)
                #pragma unroll
                for (int sm = 0; sm < 2; ++sm)
                    acc[cn][sm] = __builtin_amdgcn_mfma_f32_16x16x32_bf16(
                        bfr[cn], af[sm][ks], acc[cn][sm], 0, 0, 0);
        }

        // Epilogue: lane owns sample (sm*16+lo16) x codes (cn*16 + hi4 + r).
        const int cBase = q * 256 + tt * 32;
        float c2v[2][4];
        #pragma unroll
        for (int cn = 0; cn < 2; ++cn)
            #pragma unroll
            for (int r = 0; r < 4; ++r)
                c2v[cn][r] = c2[cBase + cn * 16 + hi4 + r];

        #pragma unroll
        for (int sm = 0; sm < 2; ++sm) {
            float dd[2][4];
            #pragma unroll
            for (int cn = 0; cn < 2; ++cn)
                #pragma unroll
                for (int r = 0; r < 4; ++r)
                    dd[cn][r] = fmaf(-2.0f, acc[cn][sm][r], c2v[cn][r]);
            float bm = dd[0][0];
            #pragma unroll
            for (int cn = 0; cn < 2; ++cn)
                #pragma unroll
                for (int r = 0; r < 4; ++r) bm = fminf(bm, dd[cn][r]);
            bm = fminf(bm, __shfl_xor(bm, 16));
            bm = fminf(bm, __shfl_xor(bm, 32));
            const float thr = bm + TAU;
            u32 m32 = 0;
            #pragma unroll
            for (int cn = 0; cn < 2; ++cn)
                #pragma unroll
                for (int r = 0; r < 4; ++r)
                    m32 |= (dd[cn][r] < thr ? 1u : 0u) << (cn * 16 + hi4 + r);
            m32 |= __shfl_xor(m32, 16);
            m32 |= __shfl_xor(m32, 32);
            if (hi == 0) {
                const int R = sBase + w * 32 + sm * 16 + lo16;
                float2 o; o.x = bm; o.y = __uint_as_float(m32);
                summ[(size_t)R * 32 + q * 8 + tt] = o;
            }
        }
        __syncthreads();
        cur ^= 1;
    }
    #undef STAGE
}

// ---- exact fp32 refine: 2 samples/wave (32-lane halves), ballot-driven ----
__global__ __launch_bounds__(256) void vq_refine(const float* __restrict__ x,
                                                 const float* __restrict__ cb,
                                                 const float* __restrict__ c2,
                                                 const float* __restrict__ x2,
                                                 const float2* __restrict__ summ,
                                                 float* __restrict__ hist,
                                                 float* __restrict__ pd,
                                                 float* __restrict__ ps,
                                                 float* __restrict__ outq,
                                                 float* __restrict__ out_idx_f) {
    __shared__ int   cd_k[4][2][64];
    __shared__ float cd_d[4][2][64];
    __shared__ float rd[8], rs[8];

    const int wid = threadIdx.x >> 6, lane = threadIdx.x & 63;
    const int half = lane >> 5, l32 = lane & 31;
    const int s = blockIdx.x * 8 + wid * 2 + half;

    const float4* x4  = reinterpret_cast<const float4*>(x);
    const float4* cb4 = reinterpret_cast<const float4*>(cb);

    const float4 xr0 = x4[(size_t)s * 64 + l32];
    const float4 xr1 = x4[(size_t)s * 64 + 32 + l32];
    const float x2s = x2[s];

    // 32 block summaries per half (lane l32 holds block l32)
    const float2 smv = summ[(size_t)s * 32 + l32];
    float gm = smv.x;
    gm = fminf(gm, __shfl_xor(gm, 1));  gm = fminf(gm, __shfl_xor(gm, 2));
    gm = fminf(gm, __shfl_xor(gm, 4));  gm = fminf(gm, __shfl_xor(gm, 8));
    gm = fminf(gm, __shfl_xor(gm, 16));
    const float lim = gm + TAU;

    u64 ball = __ballot(smv.x <= lim);
    u32 act = (u32)(ball >> (half * 32));      // per-half active-block mask

    float m = 3.4e38f, S1 = 0.f, S2 = 0.f;
    int bk = 0, cnt = 0;

    while (act) {
        const int hb = __ffs(act) - 1; act &= act - 1;
        u32 mk = __float_as_uint(__shfl(smv.y, half * 32 + hb));
        while (mk) {
            int vc = 1;
            int b0 = __ffs(mk) - 1; mk &= mk - 1;
            int k0 = hb * 32 + b0, k1 = k0, k2 = k0, k3 = k0;
            if (mk) { int b = __ffs(mk) - 1; mk &= mk - 1; k1 = hb * 32 + b; vc = 2; }
            if (mk) { int b = __ffs(mk) - 1; mk &= mk - 1; k2 = hb * 32 + b; vc = 3; }
            if (mk) { int b = __ffs(mk) - 1; mk &= mk - 1; k3 = hb * 32 + b; vc = 4; }

            float4 a0 = cb4[(size_t)k0 * 64 + l32], b0v = cb4[(size_t)k0 * 64 + 32 + l32];
            float4 a1 = cb4[(size_t)k1 * 64 + l32], b1v = cb4[(size_t)k1 * 64 + 32 + l32];
            float4 a2 = cb4[(size_t)k2 * 64 + l32], b2v = cb4[(size_t)k2 * 64 + 32 + l32];
            float4 a3 = cb4[(size_t)k3 * 64 + l32], b3v = cb4[(size_t)k3 * 64 + 32 + l32];
            float r0 = xr0.x*a0.x + xr0.y*a0.y + xr0.z*a0.z + xr0.w*a0.w
                     + xr1.x*b0v.x + xr1.y*b0v.y + xr1.z*b0v.z + xr1.w*b0v.w;
            float r1 = xr0.x*a1.x + xr0.y*a1.y + xr0.z*a1.z + xr0.w*a1.w
                     + xr1.x*b1v.x + xr1.y*b1v.y + xr1.z*b1v.z + xr1.w*b1v.w;
            float r2 = xr0.x*a2.x + xr0.y*a2.y + xr0.z*a2.z + xr0.w*a2.w
                     + xr1.x*b2v.x + xr1.y*b2v.y + xr1.z*b2v.z + xr1.w*b2v.w;
            float r3 = xr0.x*a3.x + xr0.y*a3.y + xr0.z*a3.z + xr0.w*a3.w
                     + xr1.x*b3v.x + xr1.y*b3v.y + xr1.z*b3v.z + xr1.w*b3v.w;
            #pragma unroll
            for (int off = 1; off < 32; off <<= 1) {
                r0 += __shfl_xor(r0, off);
                r1 += __shfl_xor(r1, off);
                r2 += __shfl_xor(r2, off);
                r3 += __shfl_xor(r3, off);
            }
            float dk[4];
            dk[0] = (x2s - 2.0f * r0) + c2[k0];
            dk[1] = (x2s - 2.0f * r1) + c2[k1];
            dk[2] = (x2s - 2.0f * r2) + c2[k2];
            dk[3] = (x2s - 2.0f * r3) + c2[k3];
            int kk[4] = {k0, k1, k2, k3};

            #pragma unroll
            for (int jj = 0; jj < 4; ++jj) {
                if (jj >= vc) break;
                float d = dk[jj];
                if (l32 == 0 && cnt < 64) { cd_k[wid][half][cnt] = kk[jj]; cd_d[wid][half][cnt] = d; }
                ++cnt;
                if (S1 == 0.f)   { m = d; S1 = 1.f; S2 = 0.f; bk = kk[jj]; }
                else if (d < m)  { float f = __expf((d - m) * INV_T);
                                   S2 = f * (S2 + (m - d) * S1);
                                   S1 = S1 * f + 1.f; m = d; bk = kk[jj]; }
                else             { float e = __expf((m - d) * INV_T);
                                   S1 += e; S2 += e * (d - m); }
            }
        }
    }
    float sent = S2 * INV_T / S1 + logf(S1);
    if (l32 == 0) { rd[wid * 2 + half] = m; rs[wid * 2 + half] = sent; }

    // lane-parallel histogram update (per half)
    if (cnt > 64) cnt = 64;
    for (int c = l32; c < cnt; c += 32) {
        float dkv = cd_d[wid][half][c]; int k = cd_k[wid][half][c];
        atomicAdd(&hist[k], __expf((m - dkv) * INV_T) / S1);
    }

    // fused gather: quantized row = codebook[bk]
    reinterpret_cast<float4*>(outq)[(size_t)s * 64 + l32]      = cb4[(size_t)bk * 64 + l32];
    reinterpret_cast<float4*>(outq)[(size_t)s * 64 + 32 + l32] = cb4[(size_t)bk * 64 + 32 + l32];
    if (l32 == 0) out_idx_f[s] = (float)bk;

    __syncthreads();
    if (threadIdx.x == 0) {
        float sd = 0.f, se = 0.f;
        #pragma unroll
        for (int i = 0; i < 8; ++i) { sd += rd[i]; se += rs[i]; }
        pd[blockIdx.x] = sd;
        ps[blockIdx.x] = se;
    }
}

// -------------------------------------------------------------- finalize ----
__global__ __launch_bounds__(256) void vq_finalize(const float* __restrict__ hist,
                                                   const float* __restrict__ pd,
                                                   const float* __restrict__ ps,
                                                   float* __restrict__ loss_out) {
    float ae = 0.f, sd = 0.f, se = 0.f;
    for (int k = threadIdx.x; k < KC; k += 256) {
        float p = hist[k] * (1.0f / (float)NS);
        ae += -p * logf(p + 1e-5f);
    }
    for (int b = threadIdx.x; b < 4096; b += 256) { sd += pd[b]; se += ps[b]; }
    #pragma unroll
    for (int off = 32; off; off >>= 1) {
        ae += __shfl_xor(ae, off); sd += __shfl_xor(sd, off); se += __shfl_xor(se, off);
    }
    __shared__ float r[3][4];
    int wid = threadIdx.x >> 6, lane = threadIdx.x & 63;
    if (lane == 0) { r[0][wid] = ae; r[1][wid] = sd; r[2][wid] = se; }
    __syncthreads();
    if (threadIdx.x == 0) {
        float AE = r[0][0] + r[0][1] + r[0][2] + r[0][3];
        float SD = r[1][0] + r[1][1] + r[1][2] + r[1][3];
        float SE = r[2][0] + r[2][1] + r[2][2] + r[2][3];
        float latent = 1.25f * SD / 8388608.0f;
        loss_out[0] = latent + 0.1f * (SE * (1.0f / (float)NS) - AE);
    }
}

extern "C" void kernel_launch(void* const* d_in, const int* in_sizes, int n_in,
                              void* d_out, int out_size, void* d_ws, size_t ws_size,
                              hipStream_t stream) {
    const float* x  = (const float*)d_in[0];
    const float* cb = (const float*)d_in[1];
    float* out = (float*)d_out;
    float* ws  = (float*)d_ws;

    // bf16 scratch in d_out's quantized region (overwritten by refine later):
    u16* xb = (u16*)d_out;                       // 16 MB
    u16* ct = (u16*)(out + 4194304);             // 512 KB

    vq_xcvt<<<1024, 256, 0, stream>>>(x, xb, ws + X2_OFF);
    vq_cbprep<<<64, 256, 0, stream>>>(cb, ct, ws + C2_OFF, ws + HIST_OFF);
    vq_dist<<<1024, 256, 0, stream>>>(xb, ct, ws + C2_OFF, (float2*)(ws + SUMM_OFF));
    vq_refine<<<NS / 8, 256, 0, stream>>>(x, cb, ws + C2_OFF, ws + X2_OFF,
                                          (const float2*)(ws + SUMM_OFF),
                                          ws + HIST_OFF, ws + PD_OFF, ws + PS_OFF,
                                          out, out + 8388609);
    vq_finalize<<<1, 256, 0, stream>>>(ws + HIST_OFF, ws + PD_OFF, ws + PS_OFF,
                                       out + 8388608);
}

// Round 17
// 77.835 us; speedup vs baseline: 1.4691x; 1.0389x over previous
//
#include <hip/hip_runtime.h>
#include <math.h>

typedef unsigned short u16;
typedef unsigned int u32;
typedef unsigned long long u64;
typedef float    f32x4  __attribute__((ext_vector_type(4)));
typedef __bf16   bf16x8 __attribute__((ext_vector_type(8)));

#define NS    32768
#define KC    1024
#define INV_T 100.0f
#define TAU   1.25f

// ws layout (float offsets)
#define C2_OFF   0                          // 1024
#define X2_OFF   1024                       // 32768
#define SUMM_OFF (1024 + 32768)             // [n][32 blocks] float2 = 8 MB
#define SUMM_SZ  (NS * 32 * 2)
#define HIST_OFF (SUMM_OFF + SUMM_SZ)       // 1024
#define PD_OFF   (HIST_OFF + KC)            // 4096
#define PS_OFF   (PD_OFF + 4096)            // 4096

// Fragment-chunk layouts (16B chunks of 8 bf16):
//  xb: 1024 tiles of 32 samples; chunk = ks*128 + sub*32 + row   (8192 u16/tile)
//  ct: 32 tiles of 32 codes;     chunk = ks*128 + sub*32 + row   (8192 u16/tile)
#define XTILE_U16 8192
#define CTILE_U16 8192

__device__ __forceinline__ u16 f2bf(float f) {
    unsigned u = __float_as_uint(f);
    return (u16)((u + 0x7FFFu + ((u >> 16) & 1u)) >> 16);
}

__device__ __forceinline__ void gload_lds16(const void* g, void* l) {
    __builtin_amdgcn_global_load_lds((const __attribute__((address_space(1))) void*)g,
                                     (__attribute__((address_space(3))) void*)l, 16, 0, 0);
}

// ---- prep: blocks 0..1023 convert x -> xb tiles + x2; blocks 1024..1087 do
//      codebook (c2 + ct tiles) + hist zeroing. One kernel, one gap. ----
__global__ __launch_bounds__(256) void vq_prep(const float* __restrict__ x,
                                               const float* __restrict__ cb,
                                               u16* __restrict__ xb,
                                               u16* __restrict__ ct,
                                               float* __restrict__ x2,
                                               float* __restrict__ c2,
                                               float* __restrict__ hist) {
    const int t = threadIdx.x;
    if (blockIdx.x < 1024) {
        const int tl = blockIdx.x;            // 32-sample tile
        const float* src = x + (size_t)tl * 32 * 256;
        u16* dst = xb + (size_t)tl * XTILE_U16;
        #pragma unroll
        for (int j = 0; j < 4; ++j) {
            int row = j * 8 + (t >> 5);       // 0..31
            int kq0 = (t & 31) * 2;           // float4 index, step 2
            float sq = 0.f;
            #pragma unroll
            for (int h = 0; h < 2; ++h) {
                int kq = kq0 + h;             // 0..63
                float4 v = reinterpret_cast<const float4*>(src)[(size_t)row * 64 + kq];
                sq += v.x * v.x + v.y * v.y + v.z * v.z + v.w * v.w;
                int kk = kq * 4;
                int kss = kk >> 5, sub = (kk >> 3) & 3, half = kq & 1;
                ushort4 o;
                o.x = f2bf(v.x); o.y = f2bf(v.y); o.z = f2bf(v.z); o.w = f2bf(v.w);
                *reinterpret_cast<ushort4*>(
                    dst + ((size_t)kss * 128 + sub * 32 + row) * 8 + half * 4) = o;
            }
            sq += __shfl_xor(sq, 1);  sq += __shfl_xor(sq, 2);
            sq += __shfl_xor(sq, 4);  sq += __shfl_xor(sq, 8);
            sq += __shfl_xor(sq, 16);
            if ((t & 31) == 0) x2[tl * 32 + row] = sq;
        }
    } else {
        const int b = blockIdx.x - 1024;      // 0..63
        const int w = t >> 6, lane = t & 63;

        if (t < 16) hist[b * 16 + t] = 0.f;

        #pragma unroll
        for (int i = 0; i < 4; ++i) {
            int g = b * 16 + i * 4 + w;
            float4 v = reinterpret_cast<const float4*>(cb)[(size_t)g * 64 + lane];
            float s = v.x * v.x + v.y * v.y + v.z * v.z + v.w * v.w;
            #pragma unroll
            for (int off = 32; off; off >>= 1) s += __shfl_xor(s, off);
            if (lane == 0) c2[g] = s;
        }

        const int T = b >> 1, p = b & 1;
        #pragma unroll
        for (int i = 0; i < 2; ++i) {
            int c = p * 512 + i * 256 + t;
            int ks = c >> 7, sub = (c >> 5) & 3, row = c & 31;
            const float* srcp = cb + (size_t)(T * 32 + row) * 256 + ks * 32 + sub * 8;
            float4 a0 = *reinterpret_cast<const float4*>(srcp);
            float4 a1 = *reinterpret_cast<const float4*>(srcp + 4);
            bf16x8 v;
            v[0]=(__bf16)a0.x; v[1]=(__bf16)a0.y; v[2]=(__bf16)a0.z; v[3]=(__bf16)a0.w;
            v[4]=(__bf16)a1.x; v[5]=(__bf16)a1.y; v[6]=(__bf16)a1.z; v[7]=(__bf16)a1.w;
            *reinterpret_cast<bf16x8*>(ct + (size_t)T * CTILE_U16 + (size_t)c * 8) = v;
        }
    }
}

// ---- distance MFMA: swapped operands (codes=rows, samples=cols).
//      A (32 samples/wave) persistent in regs; B = 32-code tiles dbuf via LDS
//      (2x16KB). grid 1024 = 256 sample-groups x 4 quarters; 4 blocks/CU.
__global__ __launch_bounds__(256, 4) void vq_dist(const u16* __restrict__ xb,
                                                  const u16* __restrict__ ct,
                                                  const float* __restrict__ c2,
                                                  float2* __restrict__ summ) {
    __shared__ __align__(16) u16 Bs[2][CTILE_U16];   // 2 x 16 KB

    const int id = blockIdx.x;
    const int xcd = id & 7, j = id >> 3;
    const int sq = xcd * 32 + (j >> 2);
    const int q  = j & 3;
    const int sBase = sq * 128;

    const int t = threadIdx.x, w = t >> 6, lane = t & 63;
    const int lo16 = lane & 15, hi = lane >> 4;
    const int hi4 = hi * 4;

    #define STAGE(buf, bt)                                                        \
        do {                                                                      \
            const u16* bT_ = ct + (size_t)(bt) * CTILE_U16;                       \
            _Pragma("unroll")                                                     \
            for (int i_ = 0; i_ < 4; ++i_) {                                      \
                int c0_ = (i_ * 4 + w) * 64;                                      \
                gload_lds16(bT_ + (size_t)(c0_ + lane) * 8, &Bs[buf][c0_ * 8]);   \
            }                                                                     \
        } while (0)

    STAGE(0, q * 8);

    const u16* aT = xb + (size_t)(sq * 4 + w) * XTILE_U16;
    bf16x8 af[2][8];
    #pragma unroll
    for (int sm = 0; sm < 2; ++sm)
        #pragma unroll
        for (int ks = 0; ks < 8; ++ks)
            af[sm][ks] = *reinterpret_cast<const bf16x8*>(
                aT + ((size_t)ks * 128 + hi * 32 + sm * 16 + lo16) * 8);
    __syncthreads();

    int cur = 0;
    for (int tt = 0; tt < 8; ++tt) {
        if (tt < 7) STAGE(cur ^ 1, q * 8 + tt + 1);

        f32x4 acc[2][2];
        #pragma unroll
        for (int cn = 0; cn < 2; ++cn)
            #pragma unroll
            for (int sm = 0; sm < 2; ++sm) acc[cn][sm] = (f32x4)0.f;

        const u16* bsc = &Bs[cur][0];
        #pragma unroll
        for (int ks = 0; ks < 8; ++ks) {
            bf16x8 bfr[2];
            #pragma unroll
            for (int cn = 0; cn < 2; ++cn)
                bfr[cn] = *reinterpret_cast<const bf16x8*>(
                    &bsc[((size_t)ks * 128 + hi * 32 + cn * 16 + lo16) * 8]);
            #pragma unroll
            for (int cn = 0; cn < 2; ++cn)
                #pragma unroll
                for (int sm = 0; sm < 2; ++sm)
                    acc[cn][sm] = __builtin_amdgcn_mfma_f32_16x16x32_bf16(
                        bfr[cn], af[sm][ks], acc[cn][sm], 0, 0, 0);
        }

        const int cBase = q * 256 + tt * 32;
        float c2v[2][4];
        #pragma unroll
        for (int cn = 0; cn < 2; ++cn)
            #pragma unroll
            for (int r = 0; r < 4; ++r)
                c2v[cn][r] = c2[cBase + cn * 16 + hi4 + r];

        #pragma unroll
        for (int sm = 0; sm < 2; ++sm) {
            float dd[2][4];
            #pragma unroll
            for (int cn = 0; cn < 2; ++cn)
                #pragma unroll
                for (int r = 0; r < 4; ++r)
                    dd[cn][r] = fmaf(-2.0f, acc[cn][sm][r], c2v[cn][r]);
            float bm = dd[0][0];
            #pragma unroll
            for (int cn = 0; cn < 2; ++cn)
                #pragma unroll
                for (int r = 0; r < 4; ++r) bm = fminf(bm, dd[cn][r]);
            bm = fminf(bm, __shfl_xor(bm, 16));
            bm = fminf(bm, __shfl_xor(bm, 32));
            const float thr = bm + TAU;
            u32 m32 = 0;
            #pragma unroll
            for (int cn = 0; cn < 2; ++cn)
                #pragma unroll
                for (int r = 0; r < 4; ++r)
                    m32 |= (dd[cn][r] < thr ? 1u : 0u) << (cn * 16 + hi4 + r);
            m32 |= __shfl_xor(m32, 16);
            m32 |= __shfl_xor(m32, 32);
            if (hi == 0) {
                const int R = sBase + w * 32 + sm * 16 + lo16;
                float2 o; o.x = bm; o.y = __uint_as_float(m32);
                summ[(size_t)R * 32 + q * 8 + tt] = o;
            }
        }
        __syncthreads();
        cur ^= 1;
    }
    #undef STAGE
}

// ---- exact fp32 refine: 2 samples/wave (32-lane halves), ballot-driven ----
__global__ __launch_bounds__(256) void vq_refine(const float* __restrict__ x,
                                                 const float* __restrict__ cb,
                                                 const float* __restrict__ c2,
                                                 const float* __restrict__ x2,
                                                 const float2* __restrict__ summ,
                                                 float* __restrict__ hist,
                                                 float* __restrict__ pd,
                                                 float* __restrict__ ps,
                                                 float* __restrict__ outq,
                                                 float* __restrict__ out_idx_f) {
    __shared__ int   cd_k[4][2][64];
    __shared__ float cd_d[4][2][64];
    __shared__ float rd[8], rs[8];

    const int wid = threadIdx.x >> 6, lane = threadIdx.x & 63;
    const int half = lane >> 5, l32 = lane & 31;
    const int s = blockIdx.x * 8 + wid * 2 + half;

    const float4* x4  = reinterpret_cast<const float4*>(x);
    const float4* cb4 = reinterpret_cast<const float4*>(cb);

    const float4 xr0 = x4[(size_t)s * 64 + l32];
    const float4 xr1 = x4[(size_t)s * 64 + 32 + l32];
    const float x2s = x2[s];

    const float2 smv = summ[(size_t)s * 32 + l32];
    float gm = smv.x;
    gm = fminf(gm, __shfl_xor(gm, 1));  gm = fminf(gm, __shfl_xor(gm, 2));
    gm = fminf(gm, __shfl_xor(gm, 4));  gm = fminf(gm, __shfl_xor(gm, 8));
    gm = fminf(gm, __shfl_xor(gm, 16));
    const float lim = gm + TAU;

    u64 ball = __ballot(smv.x <= lim);
    u32 act = (u32)(ball >> (half * 32));

    float m = 3.4e38f, S1 = 0.f, S2 = 0.f;
    int bk = 0, cnt = 0;

    while (act) {
        const int hb = __ffs(act) - 1; act &= act - 1;
        u32 mk = __float_as_uint(__shfl(smv.y, half * 32 + hb));
        while (mk) {
            int vc = 1;
            int b0 = __ffs(mk) - 1; mk &= mk - 1;
            int k0 = hb * 32 + b0, k1 = k0, k2 = k0, k3 = k0;
            if (mk) { int b = __ffs(mk) - 1; mk &= mk - 1; k1 = hb * 32 + b; vc = 2; }
            if (mk) { int b = __ffs(mk) - 1; mk &= mk - 1; k2 = hb * 32 + b; vc = 3; }
            if (mk) { int b = __ffs(mk) - 1; mk &= mk - 1; k3 = hb * 32 + b; vc = 4; }

            float4 a0 = cb4[(size_t)k0 * 64 + l32], b0v = cb4[(size_t)k0 * 64 + 32 + l32];
            float4 a1 = cb4[(size_t)k1 * 64 + l32], b1v = cb4[(size_t)k1 * 64 + 32 + l32];
            float4 a2 = cb4[(size_t)k2 * 64 + l32], b2v = cb4[(size_t)k2 * 64 + 32 + l32];
            float4 a3 = cb4[(size_t)k3 * 64 + l32], b3v = cb4[(size_t)k3 * 64 + 32 + l32];
            float r0 = xr0.x*a0.x + xr0.y*a0.y + xr0.z*a0.z + xr0.w*a0.w
                     + xr1.x*b0v.x + xr1.y*b0v.y + xr1.z*b0v.z + xr1.w*b0v.w;
            float r1 = xr0.x*a1.x + xr0.y*a1.y + xr0.z*a1.z + xr0.w*a1.w
                     + xr1.x*b1v.x + xr1.y*b1v.y + xr1.z*b1v.z + xr1.w*b1v.w;
            float r2 = xr0.x*a2.x + xr0.y*a2.y + xr0.z*a2.z + xr0.w*a2.w
                     + xr1.x*b2v.x + xr1.y*b2v.y + xr1.z*b2v.z + xr1.w*b2v.w;
            float r3 = xr0.x*a3.x + xr0.y*a3.y + xr0.z*a3.z + xr0.w*a3.w
                     + xr1.x*b3v.x + xr1.y*b3v.y + xr1.z*b3v.z + xr1.w*b3v.w;
            #pragma unroll
            for (int off = 1; off < 32; off <<= 1) {
                r0 += __shfl_xor(r0, off);
                r1 += __shfl_xor(r1, off);
                r2 += __shfl_xor(r2, off);
                r3 += __shfl_xor(r3, off);
            }
            float dk[4];
            dk[0] = (x2s - 2.0f * r0) + c2[k0];
            dk[1] = (x2s - 2.0f * r1) + c2[k1];
            dk[2] = (x2s - 2.0f * r2) + c2[k2];
            dk[3] = (x2s - 2.0f * r3) + c2[k3];
            int kk[4] = {k0, k1, k2, k3};

            #pragma unroll
            for (int jj = 0; jj < 4; ++jj) {
                if (jj >= vc) break;
                float d = dk[jj];
                if (l32 == 0 && cnt < 64) { cd_k[wid][half][cnt] = kk[jj]; cd_d[wid][half][cnt] = d; }
                ++cnt;
                if (S1 == 0.f)   { m = d; S1 = 1.f; S2 = 0.f; bk = kk[jj]; }
                else if (d < m)  { float f = __expf((d - m) * INV_T);
                                   S2 = f * (S2 + (m - d) * S1);
                                   S1 = S1 * f + 1.f; m = d; bk = kk[jj]; }
                else             { float e = __expf((m - d) * INV_T);
                                   S1 += e; S2 += e * (d - m); }
            }
        }
    }
    float sent = S2 * INV_T / S1 + logf(S1);
    if (l32 == 0) { rd[wid * 2 + half] = m; rs[wid * 2 + half] = sent; }

    if (cnt > 64) cnt = 64;
    for (int c = l32; c < cnt; c += 32) {
        float dkv = cd_d[wid][half][c]; int k = cd_k[wid][half][c];
        atomicAdd(&hist[k], __expf((m - dkv) * INV_T) / S1);
    }

    reinterpret_cast<float4*>(outq)[(size_t)s * 64 + l32]      = cb4[(size_t)bk * 64 + l32];
    reinterpret_cast<float4*>(outq)[(size_t)s * 64 + 32 + l32] = cb4[(size_t)bk * 64 + 32 + l32];
    if (l32 == 0) out_idx_f[s] = (float)bk;

    __syncthreads();
    if (threadIdx.x == 0) {
        float sd = 0.f, se = 0.f;
        #pragma unroll
        for (int i = 0; i < 8; ++i) { sd += rd[i]; se += rs[i]; }
        pd[blockIdx.x] = sd;
        ps[blockIdx.x] = se;
    }
}

// -------------------------------------------------------------- finalize ----
__global__ __launch_bounds__(256) void vq_finalize(const float* __restrict__ hist,
                                                   const float* __restrict__ pd,
                                                   const float* __restrict__ ps,
                                                   float* __restrict__ loss_out) {
    float ae = 0.f, sd = 0.f, se = 0.f;
    for (int k = threadIdx.x; k < KC; k += 256) {
        float p = hist[k] * (1.0f / (float)NS);
        ae += -p * logf(p + 1e-5f);
    }
    for (int b = threadIdx.x; b < 4096; b += 256) { sd += pd[b]; se += ps[b]; }
    #pragma unroll
    for (int off = 32; off; off >>= 1) {
        ae += __shfl_xor(ae, off); sd += __shfl_xor(sd, off); se += __shfl_xor(se, off);
    }
    __shared__ float r[3][4];
    int wid = threadIdx.x >> 6, lane = threadIdx.x & 63;
    if (lane == 0) { r[0][wid] = ae; r[1][wid] = sd; r[2][wid] = se; }
    __syncthreads();
    if (threadIdx.x == 0) {
        float AE = r[0][0] + r[0][1] + r[0][2] + r[0][3];
        float SD = r[1][0] + r[1][1] + r[1][2] + r[1][3];
        float SE = r[2][0] + r[2][1] + r[2][2] + r[2][3];
        float latent = 1.25f * SD / 8388608.0f;
        loss_out[0] = latent + 0.1f * (SE * (1.0f / (float)NS) - AE);
    }
}

extern "C" void kernel_launch(void* const* d_in, const int* in_sizes, int n_in,
                              void* d_out, int out_size, void* d_ws, size_t ws_size,
                              hipStream_t stream) {
    const float* x  = (const float*)d_in[0];
    const float* cb = (const float*)d_in[1];
    float* out = (float*)d_out;
    float* ws  = (float*)d_ws;

    // bf16 scratch in d_out's quantized region (overwritten by refine later):
    u16* xb = (u16*)d_out;                       // 16 MB
    u16* ct = (u16*)(out + 4194304);             // 512 KB

    vq_prep<<<1088, 256, 0, stream>>>(x, cb, xb, ct,
                                      ws + X2_OFF, ws + C2_OFF, ws + HIST_OFF);
    vq_dist<<<1024, 256, 0, stream>>>(xb, ct, ws + C2_OFF, (float2*)(ws + SUMM_OFF));
    vq_refine<<<NS / 8, 256, 0, stream>>>(x, cb, ws + C2_OFF, ws + X2_OFF,
                                          (const float2*)(ws + SUMM_OFF),
                                          ws + HIST_OFF, ws + PD_OFF, ws + PS_OFF,
                                          out, out + 8388609);
    vq_finalize<<<1, 256, 0, stream>>>(ws + HIST_OFF, ws + PD_OFF, ws + PS_OFF,
                                       out + 8388608);
}